// Round 15
// baseline (297.365 us; speedup 1.0000x reference)
//
#include <hip/hip_runtime.h>
#include <hip/hip_bf16.h>
#include <math.h>

#define BQ 8
#define NPER 2048
#define EPER 32768
#define NTOT (BQ * NPER)          // 16384
#define ETOT (BQ * EPER)          // 262144
#define HDIM 128
#define LNUM 3
#define GTN 4096                  // gate table entries over d in [0,5), nearest-neighbor

typedef __attribute__((ext_vector_type(8))) short short8;
typedef __attribute__((ext_vector_type(4))) float f32x4;

__device__ __forceinline__ short f2bf(float x) {
    union { float f; unsigned u; } v; v.f = x;
    unsigned r = v.u + 0x7fffu + ((v.u >> 16) & 1u);
    return (short)(r >> 16);
}
__device__ __forceinline__ unsigned pk2(float lo, float hi) {
    union { __hip_bfloat162 h; unsigned u; } v;
    float2 f; f.x = lo; f.y = hi;
    v.h = __float22bfloat162_rn(f);
    return v.u;
}
__device__ __forceinline__ float bflo(unsigned v) {
    union { unsigned u; float f; } x; x.u = v << 16; return x.f;
}
__device__ __forceinline__ float bfhi(unsigned v) {
    union { unsigned u; float f; } x; x.u = v & 0xffff0000u; return x.f;
}
// softplus(x)-ln2 via HW transcendentals
__device__ __forceinline__ float sspf(float x) {
    float e = __builtin_amdgcn_exp2f(x * 1.4426950408889634f);
    return 0.6931471805599453f * (__builtin_amdgcn_logf(1.0f + e) - 1.0f);
}
#define EXP2H(x) __builtin_amdgcn_exp2f(x)

// ---- LDS helpers (XOR-swizzled; act rows 256B, B rows 128B) ----
__device__ __forceinline__ short8 ldsA(const unsigned short* t, int row, int pos) {
    return *(const short8*)((const char*)t + row * 256 + ((pos * 2) ^ ((row & 7) << 4)));
}
__device__ __forceinline__ short8 ldsB(const unsigned short* t, int n, int pos) {
    return *(const short8*)((const char*)t + n * 128 + ((pos * 2) ^ ((n & 7) << 4)));
}
__device__ __forceinline__ void actW(unsigned short* t, int row, int dw, unsigned v) {
    *(unsigned*)((char*)t + row * 256 + ((dw * 4) ^ ((row & 7) << 4))) = v;
}

// ---- T14 async-STAGE split (256-thread, 16KB panel) ----
struct StageReg { uint4 v[4]; };
__device__ __forceinline__ void stage_load(StageReg& s, const unsigned short* __restrict__ src,
                                           int strideK, int kbase, int tid) {
    #pragma unroll
    for (int it = 0; it < 4; ++it) {
        int u = it * 256 + tid;
        int n = u >> 3, kd8 = u & 7;     // LINEAR source
        s.v[it] = *(const uint4*)&src[(size_t)n * strideK + kbase + kd8 * 8];
    }
}
__device__ __forceinline__ void stage_write(const StageReg& s, unsigned short* Bs, int tid) {
    #pragma unroll
    for (int it = 0; it < 4; ++it) {
        int u = it * 256 + tid;
        int n = u >> 3;
        *(uint4*)((char*)Bs + ((u * 16) ^ ((n & 7) << 4))) = s.v[it];
    }
}

// ---- 512-thread 16KB-panel stager (16B units, reg split) ----
struct StageRegH { uint4 v[2]; };
__device__ __forceinline__ void stage_loadH(StageRegH& s, const unsigned short* __restrict__ src,
                                            int strideK, int kbase, int tid) {
    #pragma unroll
    for (int it = 0; it < 2; ++it) {
        int u = it * 512 + tid;          // 1024 x 16B units
        int n = u >> 3, kd8 = u & 7;     // LINEAR source
        s.v[it] = *(const uint4*)&src[(size_t)n * strideK + kbase + kd8 * 8];
    }
}
__device__ __forceinline__ void stage_writeH(const StageRegH& s, unsigned short* Bs, int tid) {
    #pragma unroll
    for (int it = 0; it < 2; ++it) {
        int u = it * 512 + tid;
        int n = u >> 3;
        *(uint4*)((char*)Bs + ((u * 16) ^ ((n & 7) << 4))) = s.v[it];
    }
}

#define MFMA(A, B, C) __builtin_amdgcn_mfma_f32_16x16x32_bf16(A, B, C, 0, 0, 0)

// ---------------- once-per-launch prep ----------------

// merged weight prep: y=0 Wn1(K=256), y=1 Wn2, y=2 Ws1, y=3 Ws2 (all K-permuted bf16 transpose)
__global__ __launch_bounds__(256) void wprep_all_kernel(
    const float* __restrict__ Wn1, const float* __restrict__ Wn2,
    const float* __restrict__ Ws1, const float* __restrict__ Ws2,
    unsigned short* __restrict__ WT1, unsigned short* __restrict__ WT2,
    unsigned short* __restrict__ WTs1, unsigned short* __restrict__ WTs2)
{
    const float* W; unsigned short* WT; int K;
    switch (blockIdx.y) {
        case 0:  W = Wn1; WT = WT1;  K = 256; break;
        case 1:  W = Wn2; WT = WT2;  K = 128; break;
        case 2:  W = Ws1; WT = WTs1; K = 128; break;
        default: W = Ws2; WT = WTs2; K = 128; break;
    }
    int idx = blockIdx.x * 256 + threadIdx.x;
    int total = LNUM * 128 * K;
    if (idx >= total) return;
    int l = idx / (128 * K);
    int rem = idx - l * (128 * K);
    int n = rem / K;
    int p = rem - n * K;
    int half = p >> 7, pp = p & 127;
    int k = (half << 7) | ((pp >> 5) << 5) | ((pp & 1) << 4) | ((pp & 31) >> 1);
    WT[idx] = (unsigned short)f2bf(W[((size_t)l * K + k) * 128 + n]);
}

// gate table: gtab[l][idx][dword j] = bf16x2(gate*cut)
__global__ __launch_bounds__(128) void gtab_kernel(
    const float* __restrict__ We1, const float* __restrict__ be1,
    const float* __restrict__ We2, const float* __restrict__ be2,
    unsigned* __restrict__ gtab)
{
    const int idx = blockIdx.x, l = blockIdx.y, t = threadIdx.x;
    const float d = (float)idx * (5.0f / (float)GTN);
    __shared__ float rbf[64];
    __shared__ float hid[128];
    __shared__ float gv[128];
    if (t < 64) {
        float tt = d - 0.1f * (float)t;
        rbf[t] = (t < 50) ? EXP2H(-72.134752044448170f * tt * tt) : 0.0f;
    }
    __syncthreads();
    float acc = be1[l * 128 + t];
    for (int k = 0; k < 50; ++k)
        acc = fmaf(rbf[k], We1[((size_t)l * 50 + k) * 128 + t], acc);
    hid[t] = sspf(acc);
    __syncthreads();
    float g = be2[l * 128 + t];
    for (int k = 0; k < 128; ++k)
        g = fmaf(hid[k], We2[((size_t)l * 128 + k) * 128 + t], g);
    float cut = 1.0f / (1.0f + EXP2H(7.2134752044448170f * (d - 3.5f)));
    gv[t] = g * cut;
    __syncthreads();
    if (t < 64) {
        int fp = t >> 4, l15 = t & 15;
        gtab[((size_t)(l * GTN + idx)) * 64 + t] = pk2(gv[fp * 32 + l15], gv[fp * 32 + 16 + l15]);
    }
}

__global__ __launch_bounds__(256) void init_nodes_kernel(
    const int* __restrict__ nodes, const float* __restrict__ emb,
    float* __restrict__ node_state, unsigned short* __restrict__ nsb)
{
    int idx = blockIdx.x * 256 + threadIdx.x;
    int n = idx >> 7, p = idx & 127;
    int j = ((p >> 5) << 5) | ((p & 1) << 4) | ((p & 31) >> 1);
    float v = emb[(size_t)nodes[n] * 128 + j];
    nsb[idx] = (unsigned short)f2bf(v);
    node_state[(n << 7) + j] = v;
}

__global__ __launch_bounds__(256) void count_kernel(const int* __restrict__ ae, int* __restrict__ cnt)
{
    int g = blockIdx.x * 256 + threadIdx.x;
    int b = g >> 15;
    atomicAdd(&cnt[ae[2 * g + 1] + b * NPER], 1);
}

__global__ __launch_bounds__(1024) void scan_kernel(
    const int* __restrict__ cnt, int* __restrict__ segs, int* __restrict__ cursor)
{
    __shared__ int part[1024];
    int t = threadIdx.x;
    int base = t * 16;
    int s = 0;
    #pragma unroll
    for (int i = 0; i < 16; ++i) s += cnt[base + i];
    part[t] = s;
    __syncthreads();
    for (int ofs = 1; ofs < 1024; ofs <<= 1) {
        int v = part[t];
        int add = (t >= ofs) ? part[t - ofs] : 0;
        __syncthreads();
        part[t] = v + add;
        __syncthreads();
    }
    int run = part[t] - s;
    #pragma unroll
    for (int i = 0; i < 16; ++i) {
        segs[base + i] = run;
        cursor[base + i] = run;
        run += cnt[base + i];
    }
    if (t == 1023) segs[NTOT] = run;
}

__global__ __launch_bounds__(256) void scatter_kernel(
    const int* __restrict__ ae, const float* __restrict__ aef, int* __restrict__ cursor,
    int* __restrict__ ssend, int* __restrict__ srecv, float* __restrict__ sdv)
{
    int g = blockIdx.x * 256 + threadIdx.x;
    int b = g >> 15;
    int sn = ae[2 * g] + b * NPER, rv = ae[2 * g + 1] + b * NPER;
    int pos = atomicAdd(&cursor[rv], 1);
    ssend[pos] = sn; srecv[pos] = rv;
    sdv[pos] = aef[g];
}

// ---------------- layer-0 node projections ----------------

__global__ __launch_bounds__(256, 3) void nodeproj_kernel(
    const unsigned short* __restrict__ nsb,
    const unsigned short* __restrict__ WT1, const float* __restrict__ bn1,
    unsigned* __restrict__ sprojP, unsigned* __restrict__ rprojP)
{
    __shared__ unsigned short Bs[2][64 * 128];
    const int tid = threadIdx.x;
    const int n0 = blockIdx.x * 64;
    const int wv = tid >> 6, l = tid & 63, l15 = l & 15, l4 = l >> 4;
    const int er = wv * 16 + l15, crow = wv * 16 + l4 * 4;

    short8 a[4];
    #pragma unroll
    for (int ks = 0; ks < 4; ++ks)
        a[ks] = *(const short8*)&nsb[(size_t)(n0 + er) * 128 + ks * 32 + l4 * 8];

    StageReg sr;
    stage_load(sr, WT1, 256, 0, tid);
    stage_write(sr, Bs[0], tid);
    __syncthreads();

    f32x4 cs[8] = {}, cr[8] = {};
    stage_load(sr, WT1, 256, 64, tid);
    #pragma unroll
    for (int ks = 0; ks < 2; ++ks)
        #pragma unroll
        for (int f = 0; f < 8; ++f)
            cs[f] = MFMA(a[ks], ldsB(Bs[0], f * 16 + l15, ks * 32 + l4 * 8), cs[f]);
    stage_write(sr, Bs[1], tid);
    __syncthreads();
    stage_load(sr, WT1, 256, 128, tid);
    #pragma unroll
    for (int ks = 0; ks < 2; ++ks)
        #pragma unroll
        for (int f = 0; f < 8; ++f)
            cs[f] = MFMA(a[2 + ks], ldsB(Bs[1], f * 16 + l15, ks * 32 + l4 * 8), cs[f]);
    stage_write(sr, Bs[0], tid);
    __syncthreads();
    stage_load(sr, WT1, 256, 192, tid);
    #pragma unroll
    for (int ks = 0; ks < 2; ++ks)
        #pragma unroll
        for (int f = 0; f < 8; ++f)
            cr[f] = MFMA(a[ks], ldsB(Bs[0], f * 16 + l15, ks * 32 + l4 * 8), cr[f]);
    stage_write(sr, Bs[1], tid);
    __syncthreads();
    #pragma unroll
    for (int ks = 0; ks < 2; ++ks)
        #pragma unroll
        for (int f = 0; f < 8; ++f)
            cr[f] = MFMA(a[2 + ks], ldsB(Bs[1], f * 16 + l15, ks * 32 + l4 * 8), cr[f]);

    #pragma unroll
    for (int fp = 0; fp < 4; ++fp) {
        float bl = bn1[fp * 32 + l15], bh = bn1[fp * 32 + 16 + l15];
        #pragma unroll
        for (int r = 0; r < 4; ++r) {
            size_t o = (size_t)(n0 + crow + r) * 64 + fp * 16 + l15;
            sprojP[o] = pk2(cs[2 * fp][r] + bl, cs[2 * fp + 1][r] + bh);
            rprojP[o] = pk2(cr[2 * fp][r], cr[2 * fp + 1][r]);
        }
    }
}

// ---------------- per-layer: edge messages + fused segment-sum (512 thr, reg-A) ----------------

__global__ __launch_bounds__(512, 6) void edge_mfma_kernel(
    const unsigned* __restrict__ sprojP, const unsigned* __restrict__ rprojP,
    const int* __restrict__ ssend, const int* __restrict__ srecv,
    const float* __restrict__ sdv,
    const unsigned short* __restrict__ WT2, const float* __restrict__ bn2,
    const unsigned* __restrict__ gtab,
    float* __restrict__ msum)
{
    __shared__ unsigned h1u[128 * 64];         // 32 KB message buffer [row][dword]
    __shared__ unsigned short Bs[64 * 128];    // 16 KB B panel (half WT2)
    __shared__ int rls[128];
    __shared__ short segstart[132];
    __shared__ int nseg_s;
    const int tid = threadIdx.x;
    const int e0 = blockIdx.x * 128;
    const int wv = tid >> 6, l = tid & 63, l15 = l & 15, l4 = l >> 4;
    const int er = wv * 16 + l15;
    const int crow = wv * 16 + l4 * 4;

    StageRegH sr;
    stage_loadH(sr, WT2, 128, 0, tid);
    if (tid < 128) rls[tid] = srecv[e0 + tid];

    // gather + ssp directly into A-fragments
    const int sn = ssend[e0 + er], rn = srecv[e0 + er];
    short8 afr[4];
    #pragma unroll
    for (int ks = 0; ks < 4; ++ks) {
        uint4 sp = *(const uint4*)&sprojP[(size_t)sn * 64 + ks * 16 + l4 * 4];
        uint4 rp = *(const uint4*)&rprojP[(size_t)rn * 64 + ks * 16 + l4 * 4];
        unsigned su[4] = {sp.x, sp.y, sp.z, sp.w};
        unsigned ru[4] = {rp.x, rp.y, rp.z, rp.w};
        union { short8 s; unsigned u[4]; } A;
        #pragma unroll
        for (int j = 0; j < 4; ++j)
            A.u[j] = pk2(sspf(bflo(su[j]) + bflo(ru[j])),
                         sspf(bfhi(su[j]) + bfhi(ru[j])));
        afr[ks] = A.s;
    }
    stage_writeH(sr, Bs, tid);
    __syncthreads();                           // barrier 1

    if (wv == 7) {
        bool f0 = (l == 0) || (rls[l] != rls[l - 1]);
        bool f1 = (rls[64 + l] != rls[63 + l]);
        unsigned long long m0 = __ballot(f0);
        unsigned long long m1 = __ballot(f1);
        unsigned long long lm = (l == 63) ? 0xFFFFFFFFFFFFFFFFull >> 1
                                          : ((1ull << l) - 1);
        int n0c = __popcll(m0);
        if (f0) segstart[__popcll(m0 & lm)] = (short)l;
        if (f1) segstart[n0c + __popcll(m1 & lm)] = (short)(64 + l);
        if (l == 0) {
            int ns = n0c + __popcll(m1);
            nseg_s = ns;
            segstart[ns] = 128;
        }
    }

    int idxr[4];
    #pragma unroll
    for (int r = 0; r < 4; ++r) {
        float fia = sdv[e0 + crow + r] * ((float)GTN / 5.0f) + 0.5f;
        int ia = (int)fia; ia = (ia > GTN - 1) ? GTN - 1 : ia;
        idxr[r] = ia;
    }

    f32x4 m0f[8] = {};
    StageRegH sr2;
    stage_loadH(sr2, WT2, 128, 64, tid);
    #pragma unroll
    for (int ks = 0; ks < 2; ++ks)
        #pragma unroll
        for (int f = 0; f < 8; ++f)
            m0f[f] = MFMA(afr[ks], ldsB(Bs, f * 16 + l15, ks * 32 + l4 * 8), m0f[f]);
    __syncthreads();                           // barrier 2
    stage_writeH(sr2, Bs, tid);
    __syncthreads();                           // barrier 3
    #pragma unroll
    for (int ks = 0; ks < 2; ++ks)
        #pragma unroll
        for (int f = 0; f < 8; ++f)
            m0f[f] = MFMA(afr[2 + ks], ldsB(Bs, f * 16 + l15, ks * 32 + l4 * 8), m0f[f]);

    #pragma unroll
    for (int r = 0; r < 4; ++r) {
        const unsigned* grow = gtab + (size_t)idxr[r] * 64;
        #pragma unroll
        for (int fp = 0; fp < 4; ++fp) {
            float bl = bn2[fp * 32 + l15], bh = bn2[fp * 32 + 16 + l15];
            unsigned g = grow[fp * 16 + l15];
            h1u[(crow + r) * 64 + fp * 16 + l15] =
                pk2((m0f[2 * fp][r] + bl) * bflo(g), (m0f[2 * fp + 1][r] + bh) * bfhi(g));
        }
    }
    __syncthreads();                           // barrier 4

    {
        int ns = nseg_s;
        for (int s = wv; s < ns; s += 8) {
            int r0 = segstart[s], r1 = segstart[s + 1];
            int node = rls[r0];
            float lo = 0.0f, hi = 0.0f;
            for (int r = r0; r < r1; ++r) {
                unsigned v = h1u[r * 64 + l];
                lo += bflo(v); hi += bfhi(v);
            }
            float* dst = &msum[(size_t)node * 128 + l * 2];
            atomicAdd(dst, lo);
            atomicAdd(dst + 1, hi);
        }
    }
}

// ---------------- per-layer: state MLP + fused next-layer projection (512 thr, T14 pipelined) ----------------

__global__ __launch_bounds__(512) void node_mfma_kernel(
    const float* __restrict__ msum,
    const unsigned short* __restrict__ WTs1, const float* __restrict__ bs1,
    const unsigned short* __restrict__ WTs2, const float* __restrict__ bs2,
    float* __restrict__ node_state, unsigned short* __restrict__ nsb,
    float* __restrict__ out_l,
    const unsigned short* __restrict__ WT1n, const float* __restrict__ bn1n,
    unsigned* __restrict__ sprojP, unsigned* __restrict__ rprojP, int doproj)
{
    __shared__ unsigned short ah[64 * 128];    // 16 KB act tile (swizzled)
    __shared__ unsigned short Bs[2][64 * 128]; // 2 x 16 KB B panels
    int tid = threadIdx.x;
    int n0 = blockIdx.x * 64;
    StageRegH s1, s2;
    // P0: issue Ws1 k0; build ah from msum; write Bs0; issue Ws1 k64
    stage_loadH(s1, WTs1, 128, 0, tid);
    {
        const float2* ms2 = (const float2*)msum;
        #pragma unroll
        for (int it = 0; it < 8; ++it) {
            int idx = it * 512 + tid;
            int i = idx >> 6, u = idx & 63;
            float2 v = ms2[(size_t)(n0 + i) * 64 + u];
            *(unsigned*)((char*)ah + i * 256 + ((u * 4) ^ ((i & 7) << 4))) = pk2(v.x, v.y);
        }
    }
    stage_writeH(s1, Bs[0], tid);
    stage_loadH(s2, WTs1, 128, 64, tid);
    __syncthreads();                           // B1

    const int wv = tid >> 6, l = tid & 63, l15 = l & 15, l4 = l >> 4;
    const int rg = wv & 3, nh = wv >> 2;       // row-group, N-half
    const int er = rg * 16 + l15, crow = rg * 16 + l4 * 4;
    const int fb = nh * 4;

    // P1: c1 k0..63 (Bs0); write Bs1 (Ws1 k64); issue Ws2 k0
    f32x4 c1[4] = {};
    #pragma unroll
    for (int ks = 0; ks < 2; ++ks) {
        short8 a = ldsA(ah, er, ks * 32 + l4 * 8);
        #pragma unroll
        for (int f = 0; f < 4; ++f)
            c1[f] = MFMA(a, ldsB(Bs[0], (fb + f) * 16 + l15, ks * 32 + l4 * 8), c1[f]);
    }
    stage_writeH(s2, Bs[1], tid);
    stage_loadH(s1, WTs2, 128, 0, tid);
    __syncthreads();                           // B2
    // P2: c1 k64..127 (Bs1); write Bs0 (Ws2 k0); issue Ws2 k64
    #pragma unroll
    for (int ks = 0; ks < 2; ++ks) {
        short8 a = ldsA(ah, er, 64 + ks * 32 + l4 * 8);
        #pragma unroll
        for (int f = 0; f < 4; ++f)
            c1[f] = MFMA(a, ldsB(Bs[1], (fb + f) * 16 + l15, ks * 32 + l4 * 8), c1[f]);
    }
    stage_writeH(s1, Bs[0], tid);
    stage_loadH(s2, WTs2, 128, 64, tid);
    __syncthreads();                           // B3
    // P3: act -> ah; write Bs1 (Ws2 k64); issue WT1n k0 (if doproj)
    #pragma unroll
    for (int fp = 0; fp < 2; ++fp) {
        int fpg = nh * 2 + fp;
        float bl = bs1[fpg * 32 + l15], bh = bs1[fpg * 32 + 16 + l15];
        #pragma unroll
        for (int r = 0; r < 4; ++r)
            actW(ah, crow + r, fpg * 16 + l15,
                 pk2(sspf(c1[2 * fp][r] + bl), sspf(c1[2 * fp + 1][r] + bh)));
    }
    stage_writeH(s2, Bs[1], tid);
    if (doproj) stage_loadH(s1, WT1n, 256, 0, tid);
    __syncthreads();                           // B4
    // P4: c2 k0..63 (Bs0)
    f32x4 c2[4] = {};
    #pragma unroll
    for (int ks = 0; ks < 2; ++ks) {
        short8 a = ldsA(ah, er, ks * 32 + l4 * 8);
        #pragma unroll
        for (int f = 0; f < 4; ++f)
            c2[f] = MFMA(a, ldsB(Bs[0], (fb + f) * 16 + l15, ks * 32 + l4 * 8), c2[f]);
    }
    __syncthreads();                           // B5
    // P5: c2 k64..127 (Bs1); write Bs0 (WT1n k0); issue WT1n k64
    #pragma unroll
    for (int ks = 0; ks < 2; ++ks) {
        short8 a = ldsA(ah, er, 64 + ks * 32 + l4 * 8);
        #pragma unroll
        for (int f = 0; f < 4; ++f)
            c2[f] = MFMA(a, ldsB(Bs[1], (fb + f) * 16 + l15, ks * 32 + l4 * 8), c2[f]);
    }
    if (doproj) {
        stage_writeH(s1, Bs[0], tid);
        stage_loadH(s2, WT1n, 256, 64, tid);
    }
    __syncthreads();                           // B6
    // P6: state update; restage new state -> ah; write Bs1 (WT1n k64); issue WT1n k128
    unsigned nv[4][2];
    #pragma unroll
    for (int r = 0; r < 4; ++r) {
        int row = n0 + crow + r;
        float vv[4];
        #pragma unroll
        for (int f = 0; f < 4; ++f) {
            int n = (fb + f) * 16 + l15;
            float v = node_state[(size_t)row * 128 + n] + c2[f][r] + bs2[n];
            node_state[(size_t)row * 128 + n] = v;
            out_l[(size_t)row * 128 + n] = v;
            vv[f] = v;
        }
        #pragma unroll
        for (int fp = 0; fp < 2; ++fp) {
            unsigned p = pk2(vv[2 * fp], vv[2 * fp + 1]);
            nv[r][fp] = p;
            *(unsigned*)&nsb[(size_t)row * 128 + ((nh * 2 + fp) * 16 + l15) * 2] = p;
        }
    }
    if (!doproj) return;

    #pragma unroll
    for (int r = 0; r < 4; ++r)
        #pragma unroll
        for (int fp = 0; fp < 2; ++fp)
            actW(ah, crow + r, (nh * 2 + fp) * 16 + l15, nv[r][fp]);
    stage_writeH(s2, Bs[1], tid);
    stage_loadH(s1, WT1n, 256, 128, tid);
    __syncthreads();                           // B7
    // P7: cs = ah x (WT1n k0 | k64)  (both panels ready)
    f32x4 cs[4] = {}, cr[4] = {};
    #pragma unroll
    for (int ks = 0; ks < 2; ++ks) {
        short8 a = ldsA(ah, er, ks * 32 + l4 * 8);
        #pragma unroll
        for (int f = 0; f < 4; ++f)
            cs[f] = MFMA(a, ldsB(Bs[0], (fb + f) * 16 + l15, ks * 32 + l4 * 8), cs[f]);
    }
    #pragma unroll
    for (int ks = 0; ks < 2; ++ks) {
        short8 a = ldsA(ah, er, 64 + ks * 32 + l4 * 8);
        #pragma unroll
        for (int f = 0; f < 4; ++f)
            cs[f] = MFMA(a, ldsB(Bs[1], (fb + f) * 16 + l15, ks * 32 + l4 * 8), cs[f]);
    }
    __syncthreads();                           // B8
    // P8: write Bs0 (WT1n k128); issue WT1n k192
    stage_writeH(s1, Bs[0], tid);
    stage_loadH(s2, WT1n, 256, 192, tid);
    __syncthreads();                           // B9
    // P9: cr k0..63 (Bs0 = WT1n k128); write Bs1 (WT1n k192)
    #pragma unroll
    for (int ks = 0; ks < 2; ++ks) {
        short8 a = ldsA(ah, er, ks * 32 + l4 * 8);
        #pragma unroll
        for (int f = 0; f < 4; ++f)
            cr[f] = MFMA(a, ldsB(Bs[0], (fb + f) * 16 + l15, ks * 32 + l4 * 8), cr[f]);
    }
    stage_writeH(s2, Bs[1], tid);
    __syncthreads();                           // B10
    // P10: cr k64..127 (Bs1 = WT1n k192); store projections
    #pragma unroll
    for (int ks = 0; ks < 2; ++ks) {
        short8 a = ldsA(ah, er, 64 + ks * 32 + l4 * 8);
        #pragma unroll
        for (int f = 0; f < 4; ++f)
            cr[f] = MFMA(a, ldsB(Bs[1], (fb + f) * 16 + l15, ks * 32 + l4 * 8), cr[f]);
    }
    #pragma unroll
    for (int fp = 0; fp < 2; ++fp) {
        int fpg = nh * 2 + fp;
        float bl = bn1n[fpg * 32 + l15], bh = bn1n[fpg * 32 + 16 + l15];
        #pragma unroll
        for (int r = 0; r < 4; ++r) {
            size_t o = (size_t)(n0 + crow + r) * 64 + fpg * 16 + l15;
            sprojP[o] = pk2(cs[2 * fp][r] + bl, cs[2 * fp + 1][r] + bh);
            rprojP[o] = pk2(cr[2 * fp][r], cr[2 * fp + 1][r]);
        }
    }
}

// ---------------- host ----------------

extern "C" void kernel_launch(void* const* d_in, const int* in_sizes, int n_in,
                              void* d_out, int out_size, void* d_ws, size_t ws_size,
                              hipStream_t stream)
{
    const int*   nodes = (const int*)d_in[0];
    const int*   ae    = (const int*)d_in[1];
    const float* aef   = (const float*)d_in[2];
    const float* emb   = (const float*)d_in[5];
    const float* Wn1 = (const float*)d_in[6];  const float* bn1 = (const float*)d_in[7];
    const float* Wn2 = (const float*)d_in[8];  const float* bn2 = (const float*)d_in[9];
    const float* We1 = (const float*)d_in[10]; const float* be1 = (const float*)d_in[11];
    const float* We2 = (const float*)d_in[12]; const float* be2 = (const float*)d_in[13];
    const float* Ws1 = (const float*)d_in[14]; const float* bs1 = (const float*)d_in[15];
    const float* Ws2 = (const float*)d_in[16]; const float* bs2 = (const float*)d_in[17];
    float* out = (float*)d_out;

    char* ws = (char*)d_ws;
    const size_t MB = 1u << 20;
    float*          node_state = (float*)(ws);                    // 8 MB
    unsigned short* nsb        = (unsigned short*)(ws + 8 * MB);  // 4 MB
    float*          msum       = (float*)(ws + 12 * MB);          // 3 x 8 MB (f32)
    int*   ssend  = (int*)(ws + 36 * MB);
    int*   srecv  = (int*)(ws + 37 * MB);
    float* sdv    = (float*)(ws + 38 * MB);
    int*   cnt    = (int*)(ws + 40 * MB);
    int*   segs   = (int*)(ws + 40 * MB + 256 * 1024);
    int*   cursor = (int*)(ws + 40 * MB + 512 * 1024);
    unsigned short* WT1  = (unsigned short*)(ws + 41 * MB);       // 192 KB
    unsigned short* WT2  = (unsigned short*)(ws + 41 * MB + 256 * 1024);
    unsigned short* WTs1 = (unsigned short*)(ws + 42 * MB);
    unsigned short* WTs2 = (unsigned short*)(ws + 42 * MB + 256 * 1024);
    unsigned* sprojP = (unsigned*)(ws + 43 * MB);                 // 4 MB
    unsigned* rprojP = (unsigned*)(ws + 47 * MB);                 // 4 MB
    unsigned* gtab   = (unsigned*)(ws + 51 * MB);                 // 3 MB

    hipMemsetAsync(msum, 0, (size_t)3 * NTOT * 128 * sizeof(float), stream);
    wprep_all_kernel<<<dim3((LNUM * 128 * 256 + 255) / 256, 4), 256, 0, stream>>>(
        Wn1, Wn2, Ws1, Ws2, WT1, WT2, WTs1, WTs2);
    gtab_kernel<<<dim3(GTN, LNUM), 128, 0, stream>>>(We1, be1, We2, be2, gtab);
    init_nodes_kernel<<<NTOT * 128 / 256, 256, 0, stream>>>(nodes, emb, node_state, nsb);
    hipMemsetAsync(cnt, 0, NTOT * sizeof(int), stream);
    count_kernel<<<ETOT / 256, 256, 0, stream>>>(ae, cnt);
    scan_kernel<<<1, 1024, 0, stream>>>(cnt, segs, cursor);
    scatter_kernel<<<ETOT / 256, 256, 0, stream>>>(ae, aef, cursor, ssend, srecv, sdv);

    nodeproj_kernel<<<NTOT / 64, 256, 0, stream>>>(nsb, WT1, bn1, sprojP, rprojP);

    for (int l = 0; l < LNUM; ++l) {
        float* msl = msum + (size_t)l * NTOT * 128;
        edge_mfma_kernel<<<ETOT / 128, 512, 0, stream>>>(
            sprojP, rprojP, ssend, srecv, sdv,
            WT2 + (size_t)l * 128 * 128, bn2 + (size_t)l * 128,
            gtab + (size_t)l * GTN * 64,
            msl);
        int nl = (l + 1 < LNUM) ? (l + 1) : 0;
        node_mfma_kernel<<<NTOT / 64, 512, 0, stream>>>(
            msl,
            WTs1 + (size_t)l * 128 * 128, bs1 + (size_t)l * 128,
            WTs2 + (size_t)l * 128 * 128, bs2 + (size_t)l * 128,
            node_state, nsb, out + (size_t)l * NTOT * 128,
            WT1 + (size_t)nl * 128 * 256, bn1 + (size_t)nl * 128,
            sprojP, rprojP, (l + 1 < LNUM) ? 1 : 0);
    }
}

// Round 16
// 276.542 us; speedup vs baseline: 1.0753x; 1.0753x over previous
//
#include <hip/hip_runtime.h>
#include <hip/hip_bf16.h>
#include <math.h>

#define BQ 8
#define NPER 2048
#define EPER 32768
#define NTOT (BQ * NPER)          // 16384
#define ETOT (BQ * EPER)          // 262144
#define HDIM 128
#define LNUM 3
#define GTN 4096                  // gate table entries over d in [0,5), nearest-neighbor

typedef __attribute__((ext_vector_type(8))) short short8;
typedef __attribute__((ext_vector_type(4))) float f32x4;

__device__ __forceinline__ short f2bf(float x) {
    union { float f; unsigned u; } v; v.f = x;
    unsigned r = v.u + 0x7fffu + ((v.u >> 16) & 1u);
    return (short)(r >> 16);
}
__device__ __forceinline__ unsigned pk2(float lo, float hi) {
    union { __hip_bfloat162 h; unsigned u; } v;
    float2 f; f.x = lo; f.y = hi;
    v.h = __float22bfloat162_rn(f);
    return v.u;
}
__device__ __forceinline__ float bflo(unsigned v) {
    union { unsigned u; float f; } x; x.u = v << 16; return x.f;
}
__device__ __forceinline__ float bfhi(unsigned v) {
    union { unsigned u; float f; } x; x.u = v & 0xffff0000u; return x.f;
}
// softplus(x)-ln2 via HW transcendentals
__device__ __forceinline__ float sspf(float x) {
    float e = __builtin_amdgcn_exp2f(x * 1.4426950408889634f);
    return 0.6931471805599453f * (__builtin_amdgcn_logf(1.0f + e) - 1.0f);
}
#define EXP2H(x) __builtin_amdgcn_exp2f(x)

// ---- LDS helpers (XOR-swizzled; act rows 256B, B rows 128B) ----
__device__ __forceinline__ short8 ldsA(const unsigned short* t, int row, int pos) {
    return *(const short8*)((const char*)t + row * 256 + ((pos * 2) ^ ((row & 7) << 4)));
}
__device__ __forceinline__ short8 ldsB(const unsigned short* t, int n, int pos) {
    return *(const short8*)((const char*)t + n * 128 + ((pos * 2) ^ ((n & 7) << 4)));
}
__device__ __forceinline__ void actW(unsigned short* t, int row, int dw, unsigned v) {
    *(unsigned*)((char*)t + row * 256 + ((dw * 4) ^ ((row & 7) << 4))) = v;
}

// ---- T14 async-STAGE split (256-thread, 16KB panel) ----
struct StageReg { uint4 v[4]; };
__device__ __forceinline__ void stage_load(StageReg& s, const unsigned short* __restrict__ src,
                                           int strideK, int kbase, int tid) {
    #pragma unroll
    for (int it = 0; it < 4; ++it) {
        int u = it * 256 + tid;
        int n = u >> 3, kd8 = u & 7;     // LINEAR source
        s.v[it] = *(const uint4*)&src[(size_t)n * strideK + kbase + kd8 * 8];
    }
}
__device__ __forceinline__ void stage_write(const StageReg& s, unsigned short* Bs, int tid) {
    #pragma unroll
    for (int it = 0; it < 4; ++it) {
        int u = it * 256 + tid;
        int n = u >> 3;
        *(uint4*)((char*)Bs + ((u * 16) ^ ((n & 7) << 4))) = s.v[it];
    }
}
// 512-thread 16KB-panel stager (8B units)
__device__ __forceinline__ void stage_b64_512(const unsigned short* __restrict__ src, int strideK, int kbase,
                                              unsigned short* __restrict__ Bs, int tid) {
    #pragma unroll
    for (int it = 0; it < 4; ++it) {
        int i = it * 512 + tid;
        int n = i >> 4, kd2 = i & 15;
        uint2 v = *(const uint2*)&src[(size_t)n * strideK + kbase + kd2 * 4];
        *(uint2*)((char*)Bs + n * 128 + ((kd2 * 8) ^ ((n & 7) << 4))) = v;
    }
}

// ---- 512-thread 16KB-panel stager (16B units, reg split) ----
struct StageRegH { uint4 v[2]; };
__device__ __forceinline__ void stage_loadH(StageRegH& s, const unsigned short* __restrict__ src,
                                            int strideK, int kbase, int tid) {
    #pragma unroll
    for (int it = 0; it < 2; ++it) {
        int u = it * 512 + tid;          // 1024 x 16B units
        int n = u >> 3, kd8 = u & 7;     // LINEAR source
        s.v[it] = *(const uint4*)&src[(size_t)n * strideK + kbase + kd8 * 8];
    }
}
__device__ __forceinline__ void stage_writeH(const StageRegH& s, unsigned short* Bs, int tid) {
    #pragma unroll
    for (int it = 0; it < 2; ++it) {
        int u = it * 512 + tid;
        int n = u >> 3;
        *(uint4*)((char*)Bs + ((u * 16) ^ ((n & 7) << 4))) = s.v[it];
    }
}

#define MFMA(A, B, C) __builtin_amdgcn_mfma_f32_16x16x32_bf16(A, B, C, 0, 0, 0)

// ---------------- once-per-launch prep ----------------

// merged weight prep: y=0 Wn1(K=256), y=1 Wn2, y=2 Ws1, y=3 Ws2 (all K-permuted bf16 transpose)
__global__ __launch_bounds__(256) void wprep_all_kernel(
    const float* __restrict__ Wn1, const float* __restrict__ Wn2,
    const float* __restrict__ Ws1, const float* __restrict__ Ws2,
    unsigned short* __restrict__ WT1, unsigned short* __restrict__ WT2,
    unsigned short* __restrict__ WTs1, unsigned short* __restrict__ WTs2)
{
    const float* W; unsigned short* WT; int K;
    switch (blockIdx.y) {
        case 0:  W = Wn1; WT = WT1;  K = 256; break;
        case 1:  W = Wn2; WT = WT2;  K = 128; break;
        case 2:  W = Ws1; WT = WTs1; K = 128; break;
        default: W = Ws2; WT = WTs2; K = 128; break;
    }
    int idx = blockIdx.x * 256 + threadIdx.x;
    int total = LNUM * 128 * K;
    if (idx >= total) return;
    int l = idx / (128 * K);
    int rem = idx - l * (128 * K);
    int n = rem / K;
    int p = rem - n * K;
    int half = p >> 7, pp = p & 127;
    int k = (half << 7) | ((pp >> 5) << 5) | ((pp & 1) << 4) | ((pp & 31) >> 1);
    WT[idx] = (unsigned short)f2bf(W[((size_t)l * K + k) * 128 + n]);
}

// gate table: gtab[l][idx][dword j] = bf16x2(gate*cut)
__global__ __launch_bounds__(128) void gtab_kernel(
    const float* __restrict__ We1, const float* __restrict__ be1,
    const float* __restrict__ We2, const float* __restrict__ be2,
    unsigned* __restrict__ gtab)
{
    const int idx = blockIdx.x, l = blockIdx.y, t = threadIdx.x;
    const float d = (float)idx * (5.0f / (float)GTN);
    __shared__ float rbf[64];
    __shared__ float hid[128];
    __shared__ float gv[128];
    if (t < 64) {
        float tt = d - 0.1f * (float)t;
        rbf[t] = (t < 50) ? EXP2H(-72.134752044448170f * tt * tt) : 0.0f;
    }
    __syncthreads();
    float acc = be1[l * 128 + t];
    for (int k = 0; k < 50; ++k)
        acc = fmaf(rbf[k], We1[((size_t)l * 50 + k) * 128 + t], acc);
    hid[t] = sspf(acc);
    __syncthreads();
    float g = be2[l * 128 + t];
    for (int k = 0; k < 128; ++k)
        g = fmaf(hid[k], We2[((size_t)l * 128 + k) * 128 + t], g);
    float cut = 1.0f / (1.0f + EXP2H(7.2134752044448170f * (d - 3.5f)));
    gv[t] = g * cut;
    __syncthreads();
    if (t < 64) {
        int fp = t >> 4, l15 = t & 15;
        gtab[((size_t)(l * GTN + idx)) * 64 + t] = pk2(gv[fp * 32 + l15], gv[fp * 32 + 16 + l15]);
    }
}

__global__ __launch_bounds__(256) void init_nodes_kernel(
    const int* __restrict__ nodes, const float* __restrict__ emb,
    float* __restrict__ node_state, unsigned short* __restrict__ nsb)
{
    int idx = blockIdx.x * 256 + threadIdx.x;
    int n = idx >> 7, p = idx & 127;
    int j = ((p >> 5) << 5) | ((p & 1) << 4) | ((p & 31) >> 1);
    float v = emb[(size_t)nodes[n] * 128 + j];
    nsb[idx] = (unsigned short)f2bf(v);
    node_state[(n << 7) + j] = v;
}

__global__ __launch_bounds__(256) void count_kernel(const int* __restrict__ ae, int* __restrict__ cnt)
{
    int g = blockIdx.x * 256 + threadIdx.x;
    int b = g >> 15;
    atomicAdd(&cnt[ae[2 * g + 1] + b * NPER], 1);
}

__global__ __launch_bounds__(1024) void scan_kernel(
    const int* __restrict__ cnt, int* __restrict__ segs, int* __restrict__ cursor)
{
    __shared__ int part[1024];
    int t = threadIdx.x;
    int base = t * 16;
    int s = 0;
    #pragma unroll
    for (int i = 0; i < 16; ++i) s += cnt[base + i];
    part[t] = s;
    __syncthreads();
    for (int ofs = 1; ofs < 1024; ofs <<= 1) {
        int v = part[t];
        int add = (t >= ofs) ? part[t - ofs] : 0;
        __syncthreads();
        part[t] = v + add;
        __syncthreads();
    }
    int run = part[t] - s;
    #pragma unroll
    for (int i = 0; i < 16; ++i) {
        segs[base + i] = run;
        cursor[base + i] = run;
        run += cnt[base + i];
    }
    if (t == 1023) segs[NTOT] = run;
}

__global__ __launch_bounds__(256) void scatter_kernel(
    const int* __restrict__ ae, const float* __restrict__ aef, int* __restrict__ cursor,
    int* __restrict__ ssend, int* __restrict__ srecv, float* __restrict__ sdv)
{
    int g = blockIdx.x * 256 + threadIdx.x;
    int b = g >> 15;
    int sn = ae[2 * g] + b * NPER, rv = ae[2 * g + 1] + b * NPER;
    int pos = atomicAdd(&cursor[rv], 1);
    ssend[pos] = sn; srecv[pos] = rv;
    sdv[pos] = aef[g];
}

// ---------------- layer-0 node projections ----------------

__global__ __launch_bounds__(256, 3) void nodeproj_kernel(
    const unsigned short* __restrict__ nsb,
    const unsigned short* __restrict__ WT1, const float* __restrict__ bn1,
    unsigned* __restrict__ sprojP, unsigned* __restrict__ rprojP)
{
    __shared__ unsigned short Bs[2][64 * 128];
    const int tid = threadIdx.x;
    const int n0 = blockIdx.x * 64;
    const int wv = tid >> 6, l = tid & 63, l15 = l & 15, l4 = l >> 4;
    const int er = wv * 16 + l15, crow = wv * 16 + l4 * 4;

    short8 a[4];
    #pragma unroll
    for (int ks = 0; ks < 4; ++ks)
        a[ks] = *(const short8*)&nsb[(size_t)(n0 + er) * 128 + ks * 32 + l4 * 8];

    StageReg sr;
    stage_load(sr, WT1, 256, 0, tid);
    stage_write(sr, Bs[0], tid);
    __syncthreads();

    f32x4 cs[8] = {}, cr[8] = {};
    stage_load(sr, WT1, 256, 64, tid);
    #pragma unroll
    for (int ks = 0; ks < 2; ++ks)
        #pragma unroll
        for (int f = 0; f < 8; ++f)
            cs[f] = MFMA(a[ks], ldsB(Bs[0], f * 16 + l15, ks * 32 + l4 * 8), cs[f]);
    stage_write(sr, Bs[1], tid);
    __syncthreads();
    stage_load(sr, WT1, 256, 128, tid);
    #pragma unroll
    for (int ks = 0; ks < 2; ++ks)
        #pragma unroll
        for (int f = 0; f < 8; ++f)
            cs[f] = MFMA(a[2 + ks], ldsB(Bs[1], f * 16 + l15, ks * 32 + l4 * 8), cs[f]);
    stage_write(sr, Bs[0], tid);
    __syncthreads();
    stage_load(sr, WT1, 256, 192, tid);
    #pragma unroll
    for (int ks = 0; ks < 2; ++ks)
        #pragma unroll
        for (int f = 0; f < 8; ++f)
            cr[f] = MFMA(a[ks], ldsB(Bs[0], f * 16 + l15, ks * 32 + l4 * 8), cr[f]);
    stage_write(sr, Bs[1], tid);
    __syncthreads();
    #pragma unroll
    for (int ks = 0; ks < 2; ++ks)
        #pragma unroll
        for (int f = 0; f < 8; ++f)
            cr[f] = MFMA(a[2 + ks], ldsB(Bs[1], f * 16 + l15, ks * 32 + l4 * 8), cr[f]);

    #pragma unroll
    for (int fp = 0; fp < 4; ++fp) {
        float bl = bn1[fp * 32 + l15], bh = bn1[fp * 32 + 16 + l15];
        #pragma unroll
        for (int r = 0; r < 4; ++r) {
            size_t o = (size_t)(n0 + crow + r) * 64 + fp * 16 + l15;
            sprojP[o] = pk2(cs[2 * fp][r] + bl, cs[2 * fp + 1][r] + bh);
            rprojP[o] = pk2(cr[2 * fp][r], cr[2 * fp + 1][r]);
        }
    }
}

// ---------------- per-layer: edge messages + fused segment-sum (512 thr, reg-A) ----------------

__global__ __launch_bounds__(512, 6) void edge_mfma_kernel(
    const unsigned* __restrict__ sprojP, const unsigned* __restrict__ rprojP,
    const int* __restrict__ ssend, const int* __restrict__ srecv,
    const float* __restrict__ sdv,
    const unsigned short* __restrict__ WT2, const float* __restrict__ bn2,
    const unsigned* __restrict__ gtab,
    float* __restrict__ msum)
{
    __shared__ unsigned h1u[128 * 64];         // 32 KB message buffer [row][dword]
    __shared__ unsigned short Bs[64 * 128];    // 16 KB B panel (half WT2)
    __shared__ int rls[128];
    __shared__ short segstart[132];
    __shared__ int nseg_s;
    const int tid = threadIdx.x;
    const int e0 = blockIdx.x * 128;
    const int wv = tid >> 6, l = tid & 63, l15 = l & 15, l4 = l >> 4;
    const int er = wv * 16 + l15;
    const int crow = wv * 16 + l4 * 4;

    StageRegH sr;
    stage_loadH(sr, WT2, 128, 0, tid);
    if (tid < 128) rls[tid] = srecv[e0 + tid];

    // gather + ssp directly into A-fragments
    const int sn = ssend[e0 + er], rn = srecv[e0 + er];
    short8 afr[4];
    #pragma unroll
    for (int ks = 0; ks < 4; ++ks) {
        uint4 sp = *(const uint4*)&sprojP[(size_t)sn * 64 + ks * 16 + l4 * 4];
        uint4 rp = *(const uint4*)&rprojP[(size_t)rn * 64 + ks * 16 + l4 * 4];
        unsigned su[4] = {sp.x, sp.y, sp.z, sp.w};
        unsigned ru[4] = {rp.x, rp.y, rp.z, rp.w};
        union { short8 s; unsigned u[4]; } A;
        #pragma unroll
        for (int j = 0; j < 4; ++j)
            A.u[j] = pk2(sspf(bflo(su[j]) + bflo(ru[j])),
                         sspf(bfhi(su[j]) + bfhi(ru[j])));
        afr[ks] = A.s;
    }
    stage_writeH(sr, Bs, tid);
    __syncthreads();                           // barrier 1

    if (wv == 7) {
        bool f0 = (l == 0) || (rls[l] != rls[l - 1]);
        bool f1 = (rls[64 + l] != rls[63 + l]);
        unsigned long long m0 = __ballot(f0);
        unsigned long long m1 = __ballot(f1);
        unsigned long long lm = (l == 63) ? 0xFFFFFFFFFFFFFFFFull >> 1
                                          : ((1ull << l) - 1);
        int n0c = __popcll(m0);
        if (f0) segstart[__popcll(m0 & lm)] = (short)l;
        if (f1) segstart[n0c + __popcll(m1 & lm)] = (short)(64 + l);
        if (l == 0) {
            int ns = n0c + __popcll(m1);
            nseg_s = ns;
            segstart[ns] = 128;
        }
    }

    int idxr[4];
    #pragma unroll
    for (int r = 0; r < 4; ++r) {
        float fia = sdv[e0 + crow + r] * ((float)GTN / 5.0f) + 0.5f;
        int ia = (int)fia; ia = (ia > GTN - 1) ? GTN - 1 : ia;
        idxr[r] = ia;
    }

    f32x4 m0f[8] = {};
    StageRegH sr2;
    stage_loadH(sr2, WT2, 128, 64, tid);
    #pragma unroll
    for (int ks = 0; ks < 2; ++ks)
        #pragma unroll
        for (int f = 0; f < 8; ++f)
            m0f[f] = MFMA(afr[ks], ldsB(Bs, f * 16 + l15, ks * 32 + l4 * 8), m0f[f]);
    __syncthreads();                           // barrier 2
    stage_writeH(sr2, Bs, tid);
    __syncthreads();                           // barrier 3
    #pragma unroll
    for (int ks = 0; ks < 2; ++ks)
        #pragma unroll
        for (int f = 0; f < 8; ++f)
            m0f[f] = MFMA(afr[2 + ks], ldsB(Bs, f * 16 + l15, ks * 32 + l4 * 8), m0f[f]);

    #pragma unroll
    for (int r = 0; r < 4; ++r) {
        const unsigned* grow = gtab + (size_t)idxr[r] * 64;
        #pragma unroll
        for (int fp = 0; fp < 4; ++fp) {
            float bl = bn2[fp * 32 + l15], bh = bn2[fp * 32 + 16 + l15];
            unsigned g = grow[fp * 16 + l15];
            h1u[(crow + r) * 64 + fp * 16 + l15] =
                pk2((m0f[2 * fp][r] + bl) * bflo(g), (m0f[2 * fp + 1][r] + bh) * bfhi(g));
        }
    }
    __syncthreads();                           // barrier 4

    {
        int ns = nseg_s;
        for (int s = wv; s < ns; s += 8) {
            int r0 = segstart[s], r1 = segstart[s + 1];
            int node = rls[r0];
            float lo = 0.0f, hi = 0.0f;
            for (int r = r0; r < r1; ++r) {
                unsigned v = h1u[r * 64 + l];
                lo += bflo(v); hi += bfhi(v);
            }
            float* dst = &msum[(size_t)node * 128 + l * 2];
            atomicAdd(dst, lo);
            atomicAdd(dst + 1, hi);
        }
    }
}

// ---------------- per-layer: state MLP + fused next-layer projection (512 thr, N-split) ----------------

__global__ __launch_bounds__(512, 2) void node_mfma_kernel(
    const float* __restrict__ msum,
    const unsigned short* __restrict__ WTs1, const float* __restrict__ bs1,
    const unsigned short* __restrict__ WTs2, const float* __restrict__ bs2,
    float* __restrict__ node_state, unsigned short* __restrict__ nsb,
    float* __restrict__ out_l,
    const unsigned short* __restrict__ WT1n, const float* __restrict__ bn1n,
    unsigned* __restrict__ sprojP, unsigned* __restrict__ rprojP, int doproj)
{
    __shared__ unsigned short ah[64 * 128];    // 16 KB act tile (swizzled)
    __shared__ unsigned short Bs[128 * 64];    // 16 KB B panel
    int tid = threadIdx.x;
    int n0 = blockIdx.x * 64;
    {
        const float2* ms2 = (const float2*)msum;
        #pragma unroll
        for (int it = 0; it < 8; ++it) {
            int idx = it * 512 + tid;
            int i = idx >> 6, u = idx & 63;
            float2 v = ms2[(size_t)(n0 + i) * 64 + u];
            *(unsigned*)((char*)ah + i * 256 + ((u * 4) ^ ((i & 7) << 4))) = pk2(v.x, v.y);
        }
    }
    __syncthreads();
    const int wv = tid >> 6, l = tid & 63, l15 = l & 15, l4 = l >> 4;
    const int rg = wv & 3, nh = wv >> 2;       // row-group, N-half
    const int er = rg * 16 + l15, crow = rg * 16 + l4 * 4;
    const int fb = nh * 4;                     // frag base (N-half)

    f32x4 c1[4] = {};
    #pragma unroll
    for (int c = 0; c < 2; ++c) {
        stage_b64_512(WTs1, 128, c * 64, Bs, tid);
        __syncthreads();
        #pragma unroll
        for (int ks = 0; ks < 2; ++ks) {
            short8 a = ldsA(ah, er, c * 64 + ks * 32 + l4 * 8);
            #pragma unroll
            for (int f = 0; f < 4; ++f)
                c1[f] = MFMA(a, ldsB(Bs, (fb + f) * 16 + l15, ks * 32 + l4 * 8), c1[f]);
        }
        __syncthreads();
    }
    #pragma unroll
    for (int fp = 0; fp < 2; ++fp) {
        int fpg = nh * 2 + fp;
        float bl = bs1[fpg * 32 + l15], bh = bs1[fpg * 32 + 16 + l15];
        #pragma unroll
        for (int r = 0; r < 4; ++r)
            actW(ah, crow + r, fpg * 16 + l15,
                 pk2(sspf(c1[2 * fp][r] + bl), sspf(c1[2 * fp + 1][r] + bh)));
    }
    __syncthreads();

    f32x4 c2[4] = {};
    #pragma unroll
    for (int c = 0; c < 2; ++c) {
        stage_b64_512(WTs2, 128, c * 64, Bs, tid);
        __syncthreads();
        #pragma unroll
        for (int ks = 0; ks < 2; ++ks) {
            short8 a = ldsA(ah, er, c * 64 + ks * 32 + l4 * 8);
            #pragma unroll
            for (int f = 0; f < 4; ++f)
                c2[f] = MFMA(a, ldsB(Bs, (fb + f) * 16 + l15, ks * 32 + l4 * 8), c2[f]);
        }
        __syncthreads();
    }

    // state update (this wave's 16 rows x its 64 features)
    unsigned nv[4][2];
    #pragma unroll
    for (int r = 0; r < 4; ++r) {
        int row = n0 + crow + r;
        float vv[4];
        #pragma unroll
        for (int f = 0; f < 4; ++f) {
            int n = (fb + f) * 16 + l15;
            float v = node_state[(size_t)row * 128 + n] + c2[f][r] + bs2[n];
            node_state[(size_t)row * 128 + n] = v;
            out_l[(size_t)row * 128 + n] = v;
            vv[f] = v;
        }
        #pragma unroll
        for (int fp = 0; fp < 2; ++fp) {
            unsigned p = pk2(vv[2 * fp], vv[2 * fp + 1]);
            nv[r][fp] = p;
            *(unsigned*)&nsb[(size_t)row * 128 + ((nh * 2 + fp) * 16 + l15) * 2] = p;
        }
    }

    if (!doproj) return;

    // re-stage new state into ah for next-layer projection GEMMs
    #pragma unroll
    for (int r = 0; r < 4; ++r)
        #pragma unroll
        for (int fp = 0; fp < 2; ++fp)
            actW(ah, crow + r, (nh * 2 + fp) * 16 + l15, nv[r][fp]);

    f32x4 cs[4] = {}, cr[4] = {};
    #pragma unroll
    for (int c = 0; c < 2; ++c) {
        stage_b64_512(WT1n, 256, c * 64, Bs, tid);
        __syncthreads();
        #pragma unroll
        for (int ks = 0; ks < 2; ++ks) {
            short8 a = ldsA(ah, er, c * 64 + ks * 32 + l4 * 8);
            #pragma unroll
            for (int f = 0; f < 4; ++f)
                cs[f] = MFMA(a, ldsB(Bs, (fb + f) * 16 + l15, ks * 32 + l4 * 8), cs[f]);
        }
        __syncthreads();
    }
    #pragma unroll
    for (int c = 0; c < 2; ++c) {
        stage_b64_512(WT1n, 256, 128 + c * 64, Bs, tid);
        __syncthreads();
        #pragma unroll
        for (int ks = 0; ks < 2; ++ks) {
            short8 a = ldsA(ah, er, c * 64 + ks * 32 + l4 * 8);
            #pragma unroll
            for (int f = 0; f < 4; ++f)
                cr[f] = MFMA(a, ldsB(Bs, (fb + f) * 16 + l15, ks * 32 + l4 * 8), cr[f]);
        }
        __syncthreads();
    }

    #pragma unroll
    for (int fp = 0; fp < 2; ++fp) {
        int fpg = nh * 2 + fp;
        float bl = bn1n[fpg * 32 + l15], bh = bn1n[fpg * 32 + 16 + l15];
        #pragma unroll
        for (int r = 0; r < 4; ++r) {
            size_t o = (size_t)(n0 + crow + r) * 64 + fpg * 16 + l15;
            sprojP[o] = pk2(cs[2 * fp][r] + bl, cs[2 * fp + 1][r] + bh);
            rprojP[o] = pk2(cr[2 * fp][r], cr[2 * fp + 1][r]);
        }
    }
}

// ---------------- host ----------------

extern "C" void kernel_launch(void* const* d_in, const int* in_sizes, int n_in,
                              void* d_out, int out_size, void* d_ws, size_t ws_size,
                              hipStream_t stream)
{
    const int*   nodes = (const int*)d_in[0];
    const int*   ae    = (const int*)d_in[1];
    const float* aef   = (const float*)d_in[2];
    const float* emb   = (const float*)d_in[5];
    const float* Wn1 = (const float*)d_in[6];  const float* bn1 = (const float*)d_in[7];
    const float* Wn2 = (const float*)d_in[8];  const float* bn2 = (const float*)d_in[9];
    const float* We1 = (const float*)d_in[10]; const float* be1 = (const float*)d_in[11];
    const float* We2 = (const float*)d_in[12]; const float* be2 = (const float*)d_in[13];
    const float* Ws1 = (const float*)d_in[14]; const float* bs1 = (const float*)d_in[15];
    const float* Ws2 = (const float*)d_in[16]; const float* bs2 = (const float*)d_in[17];
    float* out = (float*)d_out;

    char* ws = (char*)d_ws;
    const size_t MB = 1u << 20;
    float*          node_state = (float*)(ws);                    // 8 MB
    unsigned short* nsb        = (unsigned short*)(ws + 8 * MB);  // 4 MB
    float*          msum       = (float*)(ws + 12 * MB);          // 3 x 8 MB (f32)
    int*   ssend  = (int*)(ws + 36 * MB);
    int*   srecv  = (int*)(ws + 37 * MB);
    float* sdv    = (float*)(ws + 38 * MB);
    int*   cnt    = (int*)(ws + 40 * MB);
    int*   segs   = (int*)(ws + 40 * MB + 256 * 1024);
    int*   cursor = (int*)(ws + 40 * MB + 512 * 1024);
    unsigned short* WT1  = (unsigned short*)(ws + 41 * MB);       // 192 KB
    unsigned short* WT2  = (unsigned short*)(ws + 41 * MB + 256 * 1024);
    unsigned short* WTs1 = (unsigned short*)(ws + 42 * MB);
    unsigned short* WTs2 = (unsigned short*)(ws + 42 * MB + 256 * 1024);
    unsigned* sprojP = (unsigned*)(ws + 43 * MB);                 // 4 MB
    unsigned* rprojP = (unsigned*)(ws + 47 * MB);                 // 4 MB
    unsigned* gtab   = (unsigned*)(ws + 51 * MB);                 // 3 MB

    hipMemsetAsync(msum, 0, (size_t)3 * NTOT * 128 * sizeof(float), stream);
    wprep_all_kernel<<<dim3((LNUM * 128 * 256 + 255) / 256, 4), 256, 0, stream>>>(
        Wn1, Wn2, Ws1, Ws2, WT1, WT2, WTs1, WTs2);
    gtab_kernel<<<dim3(GTN, LNUM), 128, 0, stream>>>(We1, be1, We2, be2, gtab);
    init_nodes_kernel<<<NTOT * 128 / 256, 256, 0, stream>>>(nodes, emb, node_state, nsb);
    hipMemsetAsync(cnt, 0, NTOT * sizeof(int), stream);
    count_kernel<<<ETOT / 256, 256, 0, stream>>>(ae, cnt);
    scan_kernel<<<1, 1024, 0, stream>>>(cnt, segs, cursor);
    scatter_kernel<<<ETOT / 256, 256, 0, stream>>>(ae, aef, cursor, ssend, srecv, sdv);

    nodeproj_kernel<<<NTOT / 64, 256, 0, stream>>>(nsb, WT1, bn1, sprojP, rprojP);

    for (int l = 0; l < LNUM; ++l) {
        float* msl = msum + (size_t)l * NTOT * 128;
        edge_mfma_kernel<<<ETOT / 128, 512, 0, stream>>>(
            sprojP, rprojP, ssend, srecv, sdv,
            WT2 + (size_t)l * 128 * 128, bn2 + (size_t)l * 128,
            gtab + (size_t)l * GTN * 64,
            msl);
        int nl = (l + 1 < LNUM) ? (l + 1) : 0;
        node_mfma_kernel<<<NTOT / 64, 512, 0, stream>>>(
            msl,
            WTs1 + (size_t)l * 128 * 128, bs1 + (size_t)l * 128,
            WTs2 + (size_t)l * 128 * 128, bs2 + (size_t)l * 128,
            node_state, nsb, out + (size_t)l * NTOT * 128,
            WT1 + (size_t)nl * 128 * 256, bn1 + (size_t)nl * 128,
            sprojP, rprojP, (l + 1 < LNUM) ? 1 : 0);
    }
}

// Round 17
// 240.533 us; speedup vs baseline: 1.2363x; 1.1497x over previous
//
#include <hip/hip_runtime.h>
#include <hip/hip_bf16.h>
#include <math.h>

#define BQ 8
#define NPER 2048
#define EPER 32768
#define NTOT (BQ * NPER)          // 16384
#define ETOT (BQ * EPER)          // 262144
#define HDIM 128
#define LNUM 3
#define GTN 4096                  // gate table entries over d in [0,5), nearest-neighbor

typedef __attribute__((ext_vector_type(8))) short short8;
typedef __attribute__((ext_vector_type(4))) float f32x4;

__device__ __forceinline__ short f2bf(float x) {
    union { float f; unsigned u; } v; v.f = x;
    unsigned r = v.u + 0x7fffu + ((v.u >> 16) & 1u);
    return (short)(r >> 16);
}
__device__ __forceinline__ unsigned pk2(float lo, float hi) {
    union { __hip_bfloat162 h; unsigned u; } v;
    float2 f; f.x = lo; f.y = hi;
    v.h = __float22bfloat162_rn(f);
    return v.u;
}
__device__ __forceinline__ float bflo(unsigned v) {
    union { unsigned u; float f; } x; x.u = v << 16; return x.f;
}
__device__ __forceinline__ float bfhi(unsigned v) {
    union { unsigned u; float f; } x; x.u = v & 0xffff0000u; return x.f;
}
// softplus(x)-ln2 via HW transcendentals
__device__ __forceinline__ float sspf(float x) {
    float e = __builtin_amdgcn_exp2f(x * 1.4426950408889634f);
    return 0.6931471805599453f * (__builtin_amdgcn_logf(1.0f + e) - 1.0f);
}
#define EXP2H(x) __builtin_amdgcn_exp2f(x)

// ---- LDS helpers (XOR-swizzled; act rows 256B, B rows 128B) ----
__device__ __forceinline__ short8 ldsA(const unsigned short* t, int row, int pos) {
    return *(const short8*)((const char*)t + row * 256 + ((pos * 2) ^ ((row & 7) << 4)));
}
__device__ __forceinline__ short8 ldsB(const unsigned short* t, int n, int pos) {
    return *(const short8*)((const char*)t + n * 128 + ((pos * 2) ^ ((n & 7) << 4)));
}
__device__ __forceinline__ void actW(unsigned short* t, int row, int dw, unsigned v) {
    *(unsigned*)((char*)t + row * 256 + ((dw * 4) ^ ((row & 7) << 4))) = v;
}

// ---- T14 async-STAGE split (256-thread, 16KB panel) ----
struct StageReg { uint4 v[4]; };
__device__ __forceinline__ void stage_load(StageReg& s, const unsigned short* __restrict__ src,
                                           int strideK, int kbase, int tid) {
    #pragma unroll
    for (int it = 0; it < 4; ++it) {
        int u = it * 256 + tid;
        int n = u >> 3, kd8 = u & 7;     // LINEAR source
        s.v[it] = *(const uint4*)&src[(size_t)n * strideK + kbase + kd8 * 8];
    }
}
__device__ __forceinline__ void stage_write(const StageReg& s, unsigned short* Bs, int tid) {
    #pragma unroll
    for (int it = 0; it < 4; ++it) {
        int u = it * 256 + tid;
        int n = u >> 3;
        *(uint4*)((char*)Bs + ((u * 16) ^ ((n & 7) << 4))) = s.v[it];
    }
}
// 512-thread 16KB-panel stager (8B units)
__device__ __forceinline__ void stage_b64_512(const unsigned short* __restrict__ src, int strideK, int kbase,
                                              unsigned short* __restrict__ Bs, int tid) {
    #pragma unroll
    for (int it = 0; it < 4; ++it) {
        int i = it * 512 + tid;
        int n = i >> 4, kd2 = i & 15;
        uint2 v = *(const uint2*)&src[(size_t)n * strideK + kbase + kd2 * 4];
        *(uint2*)((char*)Bs + n * 128 + ((kd2 * 8) ^ ((n & 7) << 4))) = v;
    }
}

// ---- 512-thread 16KB-panel stager (16B units, reg split) ----
struct StageRegH { uint4 v[2]; };
__device__ __forceinline__ void stage_loadH(StageRegH& s, const unsigned short* __restrict__ src,
                                            int strideK, int kbase, int tid) {
    #pragma unroll
    for (int it = 0; it < 2; ++it) {
        int u = it * 512 + tid;          // 1024 x 16B units
        int n = u >> 3, kd8 = u & 7;     // LINEAR source
        s.v[it] = *(const uint4*)&src[(size_t)n * strideK + kbase + kd8 * 8];
    }
}
__device__ __forceinline__ void stage_writeH(const StageRegH& s, unsigned short* Bs, int tid) {
    #pragma unroll
    for (int it = 0; it < 2; ++it) {
        int u = it * 512 + tid;
        int n = u >> 3;
        *(uint4*)((char*)Bs + ((u * 16) ^ ((n & 7) << 4))) = s.v[it];
    }
}

#define MFMA(A, B, C) __builtin_amdgcn_mfma_f32_16x16x32_bf16(A, B, C, 0, 0, 0)

// ---------------- once-per-launch prep ----------------

// merged weight prep: y=0 Wn1(K=256), y=1 Wn2, y=2 Ws1, y=3 Ws2 (all K-permuted bf16 transpose)
__global__ __launch_bounds__(256) void wprep_all_kernel(
    const float* __restrict__ Wn1, const float* __restrict__ Wn2,
    const float* __restrict__ Ws1, const float* __restrict__ Ws2,
    unsigned short* __restrict__ WT1, unsigned short* __restrict__ WT2,
    unsigned short* __restrict__ WTs1, unsigned short* __restrict__ WTs2)
{
    const float* W; unsigned short* WT; int K;
    switch (blockIdx.y) {
        case 0:  W = Wn1; WT = WT1;  K = 256; break;
        case 1:  W = Wn2; WT = WT2;  K = 128; break;
        case 2:  W = Ws1; WT = WTs1; K = 128; break;
        default: W = Ws2; WT = WTs2; K = 128; break;
    }
    int idx = blockIdx.x * 256 + threadIdx.x;
    int total = LNUM * 128 * K;
    if (idx >= total) return;
    int l = idx / (128 * K);
    int rem = idx - l * (128 * K);
    int n = rem / K;
    int p = rem - n * K;
    int half = p >> 7, pp = p & 127;
    int k = (half << 7) | ((pp >> 5) << 5) | ((pp & 1) << 4) | ((pp & 31) >> 1);
    WT[idx] = (unsigned short)f2bf(W[((size_t)l * K + k) * 128 + n]);
}

// gate table: gtab[l][idx][dword j] = bf16x2(gate*cut)
__global__ __launch_bounds__(128) void gtab_kernel(
    const float* __restrict__ We1, const float* __restrict__ be1,
    const float* __restrict__ We2, const float* __restrict__ be2,
    unsigned* __restrict__ gtab)
{
    const int idx = blockIdx.x, l = blockIdx.y, t = threadIdx.x;
    const float d = (float)idx * (5.0f / (float)GTN);
    __shared__ float rbf[64];
    __shared__ float hid[128];
    __shared__ float gv[128];
    if (t < 64) {
        float tt = d - 0.1f * (float)t;
        rbf[t] = (t < 50) ? EXP2H(-72.134752044448170f * tt * tt) : 0.0f;
    }
    __syncthreads();
    float acc = be1[l * 128 + t];
    for (int k = 0; k < 50; ++k)
        acc = fmaf(rbf[k], We1[((size_t)l * 50 + k) * 128 + t], acc);
    hid[t] = sspf(acc);
    __syncthreads();
    float g = be2[l * 128 + t];
    for (int k = 0; k < 128; ++k)
        g = fmaf(hid[k], We2[((size_t)l * 128 + k) * 128 + t], g);
    float cut = 1.0f / (1.0f + EXP2H(7.2134752044448170f * (d - 3.5f)));
    gv[t] = g * cut;
    __syncthreads();
    if (t < 64) {
        int fp = t >> 4, l15 = t & 15;
        gtab[((size_t)(l * GTN + idx)) * 64 + t] = pk2(gv[fp * 32 + l15], gv[fp * 32 + 16 + l15]);
    }
}

__global__ __launch_bounds__(256) void init_nodes_kernel(
    const int* __restrict__ nodes, const float* __restrict__ emb,
    float* __restrict__ node_state, unsigned short* __restrict__ nsb)
{
    int idx = blockIdx.x * 256 + threadIdx.x;
    int n = idx >> 7, p = idx & 127;
    int j = ((p >> 5) << 5) | ((p & 1) << 4) | ((p & 31) >> 1);
    float v = emb[(size_t)nodes[n] * 128 + j];
    nsb[idx] = (unsigned short)f2bf(v);
    node_state[(n << 7) + j] = v;
}

__global__ __launch_bounds__(256) void count_kernel(const int* __restrict__ ae, int* __restrict__ cnt)
{
    int g = blockIdx.x * 256 + threadIdx.x;
    int b = g >> 15;
    atomicAdd(&cnt[ae[2 * g + 1] + b * NPER], 1);
}

__global__ __launch_bounds__(1024) void scan_kernel(
    const int* __restrict__ cnt, int* __restrict__ segs, int* __restrict__ cursor)
{
    __shared__ int part[1024];
    int t = threadIdx.x;
    int base = t * 16;
    int s = 0;
    #pragma unroll
    for (int i = 0; i < 16; ++i) s += cnt[base + i];
    part[t] = s;
    __syncthreads();
    for (int ofs = 1; ofs < 1024; ofs <<= 1) {
        int v = part[t];
        int add = (t >= ofs) ? part[t - ofs] : 0;
        __syncthreads();
        part[t] = v + add;
        __syncthreads();
    }
    int run = part[t] - s;
    #pragma unroll
    for (int i = 0; i < 16; ++i) {
        segs[base + i] = run;
        cursor[base + i] = run;
        run += cnt[base + i];
    }
    if (t == 1023) segs[NTOT] = run;
}

__global__ __launch_bounds__(256) void scatter_kernel(
    const int* __restrict__ ae, const float* __restrict__ aef, int* __restrict__ cursor,
    int* __restrict__ ssend, int* __restrict__ srecv, float* __restrict__ sdv)
{
    int g = blockIdx.x * 256 + threadIdx.x;
    int b = g >> 15;
    int sn = ae[2 * g] + b * NPER, rv = ae[2 * g + 1] + b * NPER;
    int pos = atomicAdd(&cursor[rv], 1);
    ssend[pos] = sn; srecv[pos] = rv;
    sdv[pos] = aef[g];
}

// ---------------- layer-0 node projections ----------------

__global__ __launch_bounds__(256, 3) void nodeproj_kernel(
    const unsigned short* __restrict__ nsb,
    const unsigned short* __restrict__ WT1, const float* __restrict__ bn1,
    unsigned* __restrict__ sprojP, unsigned* __restrict__ rprojP)
{
    __shared__ unsigned short Bs[2][64 * 128];
    const int tid = threadIdx.x;
    const int n0 = blockIdx.x * 64;
    const int wv = tid >> 6, l = tid & 63, l15 = l & 15, l4 = l >> 4;
    const int er = wv * 16 + l15, crow = wv * 16 + l4 * 4;

    short8 a[4];
    #pragma unroll
    for (int ks = 0; ks < 4; ++ks)
        a[ks] = *(const short8*)&nsb[(size_t)(n0 + er) * 128 + ks * 32 + l4 * 8];

    StageReg sr;
    stage_load(sr, WT1, 256, 0, tid);
    stage_write(sr, Bs[0], tid);
    __syncthreads();

    f32x4 cs[8] = {}, cr[8] = {};
    stage_load(sr, WT1, 256, 64, tid);
    #pragma unroll
    for (int ks = 0; ks < 2; ++ks)
        #pragma unroll
        for (int f = 0; f < 8; ++f)
            cs[f] = MFMA(a[ks], ldsB(Bs[0], f * 16 + l15, ks * 32 + l4 * 8), cs[f]);
    stage_write(sr, Bs[1], tid);
    __syncthreads();
    stage_load(sr, WT1, 256, 128, tid);
    #pragma unroll
    for (int ks = 0; ks < 2; ++ks)
        #pragma unroll
        for (int f = 0; f < 8; ++f)
            cs[f] = MFMA(a[2 + ks], ldsB(Bs[1], f * 16 + l15, ks * 32 + l4 * 8), cs[f]);
    stage_write(sr, Bs[0], tid);
    __syncthreads();
    stage_load(sr, WT1, 256, 192, tid);
    #pragma unroll
    for (int ks = 0; ks < 2; ++ks)
        #pragma unroll
        for (int f = 0; f < 8; ++f)
            cr[f] = MFMA(a[ks], ldsB(Bs[0], f * 16 + l15, ks * 32 + l4 * 8), cr[f]);
    stage_write(sr, Bs[1], tid);
    __syncthreads();
    #pragma unroll
    for (int ks = 0; ks < 2; ++ks)
        #pragma unroll
        for (int f = 0; f < 8; ++f)
            cr[f] = MFMA(a[2 + ks], ldsB(Bs[1], f * 16 + l15, ks * 32 + l4 * 8), cr[f]);

    #pragma unroll
    for (int fp = 0; fp < 4; ++fp) {
        float bl = bn1[fp * 32 + l15], bh = bn1[fp * 32 + 16 + l15];
        #pragma unroll
        for (int r = 0; r < 4; ++r) {
            size_t o = (size_t)(n0 + crow + r) * 64 + fp * 16 + l15;
            sprojP[o] = pk2(cs[2 * fp][r] + bl, cs[2 * fp + 1][r] + bh);
            rprojP[o] = pk2(cr[2 * fp][r], cr[2 * fp + 1][r]);
        }
    }
}

// ---------------- per-layer: edge messages + fused segment-sum (512 thr, all-loads-at-top) ----------------

__global__ __launch_bounds__(512, 6) void edge_mfma_kernel(
    const unsigned* __restrict__ sprojP, const unsigned* __restrict__ rprojP,
    const int* __restrict__ ssend, const int* __restrict__ srecv,
    const float* __restrict__ sdv,
    const unsigned short* __restrict__ WT2, const float* __restrict__ bn2,
    const unsigned* __restrict__ gtab,
    float* __restrict__ msum)
{
    __shared__ unsigned h1u[128 * 64];         // 32 KB: first 16 KB doubles as WT2 chunk1 panel, then messages
    __shared__ unsigned short Bs[64 * 128];    // 16 KB B panel (WT2 chunk0)
    __shared__ int rls[128];
    __shared__ short segstart[132];
    __shared__ int nseg_s;
    const int tid = threadIdx.x;
    const int e0 = blockIdx.x * 128;
    const int wv = tid >> 6, l = tid & 63, l15 = l & 15, l4 = l >> 4;
    const int er = wv * 16 + l15;
    const int crow = wv * 16 + l4 * 4;
    unsigned short* Bs1 = (unsigned short*)h1u;   // WT2 chunk1 lives here until combine

    // issue ALL global loads at the top: both WT2 halves + receivers
    StageRegH sr, sr2;
    stage_loadH(sr, WT2, 128, 0, tid);
    stage_loadH(sr2, WT2, 128, 64, tid);
    if (tid < 128) rls[tid] = srecv[e0 + tid];

    // gather + ssp directly into A-fragments (hides WT2 latency)
    const int sn = ssend[e0 + er], rn = srecv[e0 + er];
    short8 afr[4];
    #pragma unroll
    for (int ks = 0; ks < 4; ++ks) {
        uint4 sp = *(const uint4*)&sprojP[(size_t)sn * 64 + ks * 16 + l4 * 4];
        uint4 rp = *(const uint4*)&rprojP[(size_t)rn * 64 + ks * 16 + l4 * 4];
        unsigned su[4] = {sp.x, sp.y, sp.z, sp.w};
        unsigned ru[4] = {rp.x, rp.y, rp.z, rp.w};
        union { short8 s; unsigned u[4]; } A;
        #pragma unroll
        for (int j = 0; j < 4; ++j)
            A.u[j] = pk2(sspf(bflo(su[j]) + bflo(ru[j])),
                         sspf(bfhi(su[j]) + bfhi(ru[j])));
        afr[ks] = A.s;
    }
    stage_writeH(sr, Bs, tid);
    stage_writeH(sr2, Bs1, tid);
    __syncthreads();                           // barrier 1: both B panels ready

    if (wv == 7) {
        bool f0 = (l == 0) || (rls[l] != rls[l - 1]);
        bool f1 = (rls[64 + l] != rls[63 + l]);
        unsigned long long m0 = __ballot(f0);
        unsigned long long m1 = __ballot(f1);
        unsigned long long lm = (l == 63) ? 0xFFFFFFFFFFFFFFFFull >> 1
                                          : ((1ull << l) - 1);
        int n0c = __popcll(m0);
        if (f0) segstart[__popcll(m0 & lm)] = (short)l;
        if (f1) segstart[n0c + __popcll(m1 & lm)] = (short)(64 + l);
        if (l == 0) {
            int ns = n0c + __popcll(m1);
            nseg_s = ns;
            segstart[ns] = 128;
        }
    }

    int idxr[4];
    #pragma unroll
    for (int r = 0; r < 4; ++r) {
        float fia = sdv[e0 + crow + r] * ((float)GTN / 5.0f) + 0.5f;
        int ia = (int)fia; ia = (ia > GTN - 1) ? GTN - 1 : ia;
        idxr[r] = ia;
    }

    // GEMM: all 4 K-slices back-to-back, no internal barriers
    f32x4 m0f[8] = {};
    #pragma unroll
    for (int ks = 0; ks < 2; ++ks)
        #pragma unroll
        for (int f = 0; f < 8; ++f)
            m0f[f] = MFMA(afr[ks], ldsB(Bs, f * 16 + l15, ks * 32 + l4 * 8), m0f[f]);
    #pragma unroll
    for (int ks = 0; ks < 2; ++ks)
        #pragma unroll
        for (int f = 0; f < 8; ++f)
            m0f[f] = MFMA(afr[2 + ks], ldsB(Bs1, f * 16 + l15, ks * 32 + l4 * 8), m0f[f]);
    __syncthreads();                           // barrier 2: h1u B-panel reads done

    // combine: msg = (m + bn2) * gate_nn -> h1u (plain [128][64-dword] layout)
    #pragma unroll
    for (int r = 0; r < 4; ++r) {
        const unsigned* grow = gtab + (size_t)idxr[r] * 64;
        #pragma unroll
        for (int fp = 0; fp < 4; ++fp) {
            float bl = bn2[fp * 32 + l15], bh = bn2[fp * 32 + 16 + l15];
            unsigned g = grow[fp * 16 + l15];
            h1u[(crow + r) * 64 + fp * 16 + l15] =
                pk2((m0f[2 * fp][r] + bl) * bflo(g), (m0f[2 * fp + 1][r] + bh) * bfhi(g));
        }
    }
    __syncthreads();                           // barrier 3

    // fused segment-sum: per-wave segments, f32 accumulate from LDS, atomicAdd to msum
    {
        int ns = nseg_s;
        for (int s = wv; s < ns; s += 8) {
            int r0 = segstart[s], r1 = segstart[s + 1];
            int node = rls[r0];
            float lo = 0.0f, hi = 0.0f;
            for (int r = r0; r < r1; ++r) {
                unsigned v = h1u[r * 64 + l];
                lo += bflo(v); hi += bfhi(v);
            }
            float* dst = &msum[(size_t)node * 128 + l * 2];
            atomicAdd(dst, lo);
            atomicAdd(dst + 1, hi);
        }
    }
}

// ---------------- per-layer: state MLP + fused next-layer projection (512 thr, N-split) ----------------

__global__ __launch_bounds__(512, 2) void node_mfma_kernel(
    const float* __restrict__ msum,
    const unsigned short* __restrict__ WTs1, const float* __restrict__ bs1,
    const unsigned short* __restrict__ WTs2, const float* __restrict__ bs2,
    float* __restrict__ node_state, unsigned short* __restrict__ nsb,
    float* __restrict__ out_l,
    const unsigned short* __restrict__ WT1n, const float* __restrict__ bn1n,
    unsigned* __restrict__ sprojP, unsigned* __restrict__ rprojP, int doproj)
{
    __shared__ unsigned short ah[64 * 128];    // 16 KB act tile (swizzled)
    __shared__ unsigned short Bs[128 * 64];    // 16 KB B panel
    int tid = threadIdx.x;
    int n0 = blockIdx.x * 64;
    {
        const float2* ms2 = (const float2*)msum;
        #pragma unroll
        for (int it = 0; it < 8; ++it) {
            int idx = it * 512 + tid;
            int i = idx >> 6, u = idx & 63;
            float2 v = ms2[(size_t)(n0 + i) * 64 + u];
            *(unsigned*)((char*)ah + i * 256 + ((u * 4) ^ ((i & 7) << 4))) = pk2(v.x, v.y);
        }
    }
    __syncthreads();
    const int wv = tid >> 6, l = tid & 63, l15 = l & 15, l4 = l >> 4;
    const int rg = wv & 3, nh = wv >> 2;       // row-group, N-half
    const int er = rg * 16 + l15, crow = rg * 16 + l4 * 4;
    const int fb = nh * 4;                     // frag base (N-half)

    f32x4 c1[4] = {};
    #pragma unroll
    for (int c = 0; c < 2; ++c) {
        stage_b64_512(WTs1, 128, c * 64, Bs, tid);
        __syncthreads();
        #pragma unroll
        for (int ks = 0; ks < 2; ++ks) {
            short8 a = ldsA(ah, er, c * 64 + ks * 32 + l4 * 8);
            #pragma unroll
            for (int f = 0; f < 4; ++f)
                c1[f] = MFMA(a, ldsB(Bs, (fb + f) * 16 + l15, ks * 32 + l4 * 8), c1[f]);
        }
        __syncthreads();
    }
    #pragma unroll
    for (int fp = 0; fp < 2; ++fp) {
        int fpg = nh * 2 + fp;
        float bl = bs1[fpg * 32 + l15], bh = bs1[fpg * 32 + 16 + l15];
        #pragma unroll
        for (int r = 0; r < 4; ++r)
            actW(ah, crow + r, fpg * 16 + l15,
                 pk2(sspf(c1[2 * fp][r] + bl), sspf(c1[2 * fp + 1][r] + bh)));
    }
    __syncthreads();

    f32x4 c2[4] = {};
    #pragma unroll
    for (int c = 0; c < 2; ++c) {
        stage_b64_512(WTs2, 128, c * 64, Bs, tid);
        __syncthreads();
        #pragma unroll
        for (int ks = 0; ks < 2; ++ks) {
            short8 a = ldsA(ah, er, c * 64 + ks * 32 + l4 * 8);
            #pragma unroll
            for (int f = 0; f < 4; ++f)
                c2[f] = MFMA(a, ldsB(Bs, (fb + f) * 16 + l15, ks * 32 + l4 * 8), c2[f]);
        }
        __syncthreads();
    }

    // state update (this wave's 16 rows x its 64 features)
    unsigned nv[4][2];
    #pragma unroll
    for (int r = 0; r < 4; ++r) {
        int row = n0 + crow + r;
        float vv[4];
        #pragma unroll
        for (int f = 0; f < 4; ++f) {
            int n = (fb + f) * 16 + l15;
            float v = node_state[(size_t)row * 128 + n] + c2[f][r] + bs2[n];
            node_state[(size_t)row * 128 + n] = v;
            out_l[(size_t)row * 128 + n] = v;
            vv[f] = v;
        }
        #pragma unroll
        for (int fp = 0; fp < 2; ++fp) {
            unsigned p = pk2(vv[2 * fp], vv[2 * fp + 1]);
            nv[r][fp] = p;
            *(unsigned*)&nsb[(size_t)row * 128 + ((nh * 2 + fp) * 16 + l15) * 2] = p;
        }
    }

    if (!doproj) return;

    // re-stage new state into ah for next-layer projection GEMMs
    #pragma unroll
    for (int r = 0; r < 4; ++r)
        #pragma unroll
        for (int fp = 0; fp < 2; ++fp)
            actW(ah, crow + r, (nh * 2 + fp) * 16 + l15, nv[r][fp]);

    f32x4 cs[4] = {}, cr[4] = {};
    #pragma unroll
    for (int c = 0; c < 2; ++c) {
        stage_b64_512(WT1n, 256, c * 64, Bs, tid);
        __syncthreads();
        #pragma unroll
        for (int ks = 0; ks < 2; ++ks) {
            short8 a = ldsA(ah, er, c * 64 + ks * 32 + l4 * 8);
            #pragma unroll
            for (int f = 0; f < 4; ++f)
                cs[f] = MFMA(a, ldsB(Bs, (fb + f) * 16 + l15, ks * 32 + l4 * 8), cs[f]);
        }
        __syncthreads();
    }
    #pragma unroll
    for (int c = 0; c < 2; ++c) {
        stage_b64_512(WT1n, 256, 128 + c * 64, Bs, tid);
        __syncthreads();
        #pragma unroll
        for (int ks = 0; ks < 2; ++ks) {
            short8 a = ldsA(ah, er, c * 64 + ks * 32 + l4 * 8);
            #pragma unroll
            for (int f = 0; f < 4; ++f)
                cr[f] = MFMA(a, ldsB(Bs, (fb + f) * 16 + l15, ks * 32 + l4 * 8), cr[f]);
        }
        __syncthreads();
    }

    #pragma unroll
    for (int fp = 0; fp < 2; ++fp) {
        int fpg = nh * 2 + fp;
        float bl = bn1n[fpg * 32 + l15], bh = bn1n[fpg * 32 + 16 + l15];
        #pragma unroll
        for (int r = 0; r < 4; ++r) {
            size_t o = (size_t)(n0 + crow + r) * 64 + fpg * 16 + l15;
            sprojP[o] = pk2(cs[2 * fp][r] + bl, cs[2 * fp + 1][r] + bh);
            rprojP[o] = pk2(cr[2 * fp][r], cr[2 * fp + 1][r]);
        }
    }
}

// ---------------- host ----------------

extern "C" void kernel_launch(void* const* d_in, const int* in_sizes, int n_in,
                              void* d_out, int out_size, void* d_ws, size_t ws_size,
                              hipStream_t stream)
{
    const int*   nodes = (const int*)d_in[0];
    const int*   ae    = (const int*)d_in[1];
    const float* aef   = (const float*)d_in[2];
    const float* emb   = (const float*)d_in[5];
    const float* Wn1 = (const float*)d_in[6];  const float* bn1 = (const float*)d_in[7];
    const float* Wn2 = (const float*)d_in[8];  const float* bn2 = (const float*)d_in[9];
    const float* We1 = (const float*)d_in[10]; const float* be1 = (const float*)d_in[11];
    const float* We2 = (const float*)d_in[12]; const float* be2 = (const float*)d_in[13];
    const float* Ws1 = (const float*)d_in[14]; const float* bs1 = (const float*)d_in[15];
    const float* Ws2 = (const float*)d_in[16]; const float* bs2 = (const float*)d_in[17];
    float* out = (float*)d_out;

    char* ws = (char*)d_ws;
    const size_t MB = 1u << 20;
    float*          node_state = (float*)(ws);                    // 8 MB
    unsigned short* nsb        = (unsigned short*)(ws + 8 * MB);  // 4 MB
    float*          msum       = (float*)(ws + 12 * MB);          // 3 x 8 MB (f32)
    int*   ssend  = (int*)(ws + 36 * MB);
    int*   srecv  = (int*)(ws + 37 * MB);
    float* sdv    = (float*)(ws + 38 * MB);
    int*   cnt    = (int*)(ws + 40 * MB);
    int*   segs   = (int*)(ws + 40 * MB + 256 * 1024);
    int*   cursor = (int*)(ws + 40 * MB + 512 * 1024);
    unsigned short* WT1  = (unsigned short*)(ws + 41 * MB);       // 192 KB
    unsigned short* WT2  = (unsigned short*)(ws + 41 * MB + 256 * 1024);
    unsigned short* WTs1 = (unsigned short*)(ws + 42 * MB);
    unsigned short* WTs2 = (unsigned short*)(ws + 42 * MB + 256 * 1024);
    unsigned* sprojP = (unsigned*)(ws + 43 * MB);                 // 4 MB
    unsigned* rprojP = (unsigned*)(ws + 47 * MB);                 // 4 MB
    unsigned* gtab   = (unsigned*)(ws + 51 * MB);                 // 3 MB

    hipMemsetAsync(msum, 0, (size_t)3 * NTOT * 128 * sizeof(float), stream);
    wprep_all_kernel<<<dim3((LNUM * 128 * 256 + 255) / 256, 4), 256, 0, stream>>>(
        Wn1, Wn2, Ws1, Ws2, WT1, WT2, WTs1, WTs2);
    gtab_kernel<<<dim3(GTN, LNUM), 128, 0, stream>>>(We1, be1, We2, be2, gtab);
    init_nodes_kernel<<<NTOT * 128 / 256, 256, 0, stream>>>(nodes, emb, node_state, nsb);
    hipMemsetAsync(cnt, 0, NTOT * sizeof(int), stream);
    count_kernel<<<ETOT / 256, 256, 0, stream>>>(ae, cnt);
    scan_kernel<<<1, 1024, 0, stream>>>(cnt, segs, cursor);
    scatter_kernel<<<ETOT / 256, 256, 0, stream>>>(ae, aef, cursor, ssend, srecv, sdv);

    nodeproj_kernel<<<NTOT / 64, 256, 0, stream>>>(nsb, WT1, bn1, sprojP, rprojP);

    for (int l = 0; l < LNUM; ++l) {
        float* msl = msum + (size_t)l * NTOT * 128;
        edge_mfma_kernel<<<ETOT / 128, 512, 0, stream>>>(
            sprojP, rprojP, ssend, srecv, sdv,
            WT2 + (size_t)l * 128 * 128, bn2 + (size_t)l * 128,
            gtab + (size_t)l * GTN * 64,
            msl);
        int nl = (l + 1 < LNUM) ? (l + 1) : 0;
        node_mfma_kernel<<<NTOT / 64, 512, 0, stream>>>(
            msl,
            WTs1 + (size_t)l * 128 * 128, bs1 + (size_t)l * 128,
            WTs2 + (size_t)l * 128 * 128, bs2 + (size_t)l * 128,
            node_state, nsb, out + (size_t)l * NTOT * 128,
            WT1 + (size_t)nl * 128 * 256, bn1 + (size_t)nl * 128,
            sprojP, rprojP, (l + 1 < LNUM) ? 1 : 0);
    }
}

// Round 18
// 238.187 us; speedup vs baseline: 1.2485x; 1.0099x over previous
//
#include <hip/hip_runtime.h>
#include <hip/hip_bf16.h>
#include <math.h>

#define BQ 8
#define NPER 2048
#define EPER 32768
#define NTOT (BQ * NPER)          // 16384
#define ETOT (BQ * EPER)          // 262144
#define HDIM 128
#define LNUM 3
#define GTN 4096                  // gate table entries over d in [0,5), nearest-neighbor

typedef __attribute__((ext_vector_type(8))) short short8;
typedef __attribute__((ext_vector_type(4))) float f32x4;

__device__ __forceinline__ short f2bf(float x) {
    union { float f; unsigned u; } v; v.f = x;
    unsigned r = v.u + 0x7fffu + ((v.u >> 16) & 1u);
    return (short)(r >> 16);
}
__device__ __forceinline__ unsigned pk2(float lo, float hi) {
    union { __hip_bfloat162 h; unsigned u; } v;
    float2 f; f.x = lo; f.y = hi;
    v.h = __float22bfloat162_rn(f);
    return v.u;
}
__device__ __forceinline__ float bflo(unsigned v) {
    union { unsigned u; float f; } x; x.u = v << 16; return x.f;
}
__device__ __forceinline__ float bfhi(unsigned v) {
    union { unsigned u; float f; } x; x.u = v & 0xffff0000u; return x.f;
}
// softplus(x)-ln2 via HW transcendentals
__device__ __forceinline__ float sspf(float x) {
    float e = __builtin_amdgcn_exp2f(x * 1.4426950408889634f);
    return 0.6931471805599453f * (__builtin_amdgcn_logf(1.0f + e) - 1.0f);
}
#define EXP2H(x) __builtin_amdgcn_exp2f(x)

// ---- LDS helpers (XOR-swizzled; act rows 256B, B rows 128B) ----
__device__ __forceinline__ short8 ldsA(const unsigned short* t, int row, int pos) {
    return *(const short8*)((const char*)t + row * 256 + ((pos * 2) ^ ((row & 7) << 4)));
}
__device__ __forceinline__ short8 ldsB(const unsigned short* t, int n, int pos) {
    return *(const short8*)((const char*)t + n * 128 + ((pos * 2) ^ ((n & 7) << 4)));
}
__device__ __forceinline__ void actW(unsigned short* t, int row, int dw, unsigned v) {
    *(unsigned*)((char*)t + row * 256 + ((dw * 4) ^ ((row & 7) << 4))) = v;
}

// ---- T14 async-STAGE split (256-thread, 16KB panel) ----
struct StageReg { uint4 v[4]; };
__device__ __forceinline__ void stage_load(StageReg& s, const unsigned short* __restrict__ src,
                                           int strideK, int kbase, int tid) {
    #pragma unroll
    for (int it = 0; it < 4; ++it) {
        int u = it * 256 + tid;
        int n = u >> 3, kd8 = u & 7;     // LINEAR source
        s.v[it] = *(const uint4*)&src[(size_t)n * strideK + kbase + kd8 * 8];
    }
}
__device__ __forceinline__ void stage_write(const StageReg& s, unsigned short* Bs, int tid) {
    #pragma unroll
    for (int it = 0; it < 4; ++it) {
        int u = it * 256 + tid;
        int n = u >> 3;
        *(uint4*)((char*)Bs + ((u * 16) ^ ((n & 7) << 4))) = s.v[it];
    }
}
// 512-thread 16KB-panel stager (8B units)
__device__ __forceinline__ void stage_b64_512(const unsigned short* __restrict__ src, int strideK, int kbase,
                                              unsigned short* __restrict__ Bs, int tid) {
    #pragma unroll
    for (int it = 0; it < 4; ++it) {
        int i = it * 512 + tid;
        int n = i >> 4, kd2 = i & 15;
        uint2 v = *(const uint2*)&src[(size_t)n * strideK + kbase + kd2 * 4];
        *(uint2*)((char*)Bs + n * 128 + ((kd2 * 8) ^ ((n & 7) << 4))) = v;
    }
}

// ---- 512-thread 16KB-panel stager (16B units, reg split) ----
struct StageRegH { uint4 v[2]; };
__device__ __forceinline__ void stage_loadH(StageRegH& s, const unsigned short* __restrict__ src,
                                            int strideK, int kbase, int tid) {
    #pragma unroll
    for (int it = 0; it < 2; ++it) {
        int u = it * 512 + tid;          // 1024 x 16B units
        int n = u >> 3, kd8 = u & 7;     // LINEAR source
        s.v[it] = *(const uint4*)&src[(size_t)n * strideK + kbase + kd8 * 8];
    }
}
__device__ __forceinline__ void stage_writeH(const StageRegH& s, unsigned short* Bs, int tid) {
    #pragma unroll
    for (int it = 0; it < 2; ++it) {
        int u = it * 512 + tid;
        int n = u >> 3;
        *(uint4*)((char*)Bs + ((u * 16) ^ ((n & 7) << 4))) = s.v[it];
    }
}

#define MFMA(A, B, C) __builtin_amdgcn_mfma_f32_16x16x32_bf16(A, B, C, 0, 0, 0)

// ---------------- once-per-launch prep ----------------

// fast grid-strided zero (replaces rocclr fillBuffer)
__global__ __launch_bounds__(256) void zero_kernel(float4* __restrict__ p, int n4)
{
    int i = blockIdx.x * 256 + threadIdx.x;
    int stride = gridDim.x * 256;
    float4 z = {0.0f, 0.0f, 0.0f, 0.0f};
    for (; i < n4; i += stride) p[i] = z;
}

// merged weight prep: y=0 Wn1(K=256), y=1 Wn2, y=2 Ws1, y=3 Ws2 (all K-permuted bf16 transpose)
__global__ __launch_bounds__(256) void wprep_all_kernel(
    const float* __restrict__ Wn1, const float* __restrict__ Wn2,
    const float* __restrict__ Ws1, const float* __restrict__ Ws2,
    unsigned short* __restrict__ WT1, unsigned short* __restrict__ WT2,
    unsigned short* __restrict__ WTs1, unsigned short* __restrict__ WTs2)
{
    const float* W; unsigned short* WT; int K;
    switch (blockIdx.y) {
        case 0:  W = Wn1; WT = WT1;  K = 256; break;
        case 1:  W = Wn2; WT = WT2;  K = 128; break;
        case 2:  W = Ws1; WT = WTs1; K = 128; break;
        default: W = Ws2; WT = WTs2; K = 128; break;
    }
    int idx = blockIdx.x * 256 + threadIdx.x;
    int total = LNUM * 128 * K;
    if (idx >= total) return;
    int l = idx / (128 * K);
    int rem = idx - l * (128 * K);
    int n = rem / K;
    int p = rem - n * K;
    int half = p >> 7, pp = p & 127;
    int k = (half << 7) | ((pp >> 5) << 5) | ((pp & 1) << 4) | ((pp & 31) >> 1);
    WT[idx] = (unsigned short)f2bf(W[((size_t)l * K + k) * 128 + n]);
}

// gate table: gtab[l][idx][dword j] = bf16x2(gate*cut)
__global__ __launch_bounds__(128) void gtab_kernel(
    const float* __restrict__ We1, const float* __restrict__ be1,
    const float* __restrict__ We2, const float* __restrict__ be2,
    unsigned* __restrict__ gtab)
{
    const int idx = blockIdx.x, l = blockIdx.y, t = threadIdx.x;
    const float d = (float)idx * (5.0f / (float)GTN);
    __shared__ float rbf[64];
    __shared__ float hid[128];
    __shared__ float gv[128];
    if (t < 64) {
        float tt = d - 0.1f * (float)t;
        rbf[t] = (t < 50) ? EXP2H(-72.134752044448170f * tt * tt) : 0.0f;
    }
    __syncthreads();
    float acc = be1[l * 128 + t];
    for (int k = 0; k < 50; ++k)
        acc = fmaf(rbf[k], We1[((size_t)l * 50 + k) * 128 + t], acc);
    hid[t] = sspf(acc);
    __syncthreads();
    float g = be2[l * 128 + t];
    for (int k = 0; k < 128; ++k)
        g = fmaf(hid[k], We2[((size_t)l * 128 + k) * 128 + t], g);
    float cut = 1.0f / (1.0f + EXP2H(7.2134752044448170f * (d - 3.5f)));
    gv[t] = g * cut;
    __syncthreads();
    if (t < 64) {
        int fp = t >> 4, l15 = t & 15;
        gtab[((size_t)(l * GTN + idx)) * 64 + t] = pk2(gv[fp * 32 + l15], gv[fp * 32 + 16 + l15]);
    }
}

__global__ __launch_bounds__(256) void init_nodes_kernel(
    const int* __restrict__ nodes, const float* __restrict__ emb,
    float* __restrict__ node_state, unsigned short* __restrict__ nsb)
{
    int idx = blockIdx.x * 256 + threadIdx.x;
    int n = idx >> 7, p = idx & 127;
    int j = ((p >> 5) << 5) | ((p & 1) << 4) | ((p & 31) >> 1);
    float v = emb[(size_t)nodes[n] * 128 + j];
    nsb[idx] = (unsigned short)f2bf(v);
    node_state[(n << 7) + j] = v;
}

__global__ __launch_bounds__(256) void count_kernel(const int* __restrict__ ae, int* __restrict__ cnt)
{
    int g = blockIdx.x * 256 + threadIdx.x;
    int b = g >> 15;
    atomicAdd(&cnt[ae[2 * g + 1] + b * NPER], 1);
}

__global__ __launch_bounds__(1024) void scan_kernel(
    const int* __restrict__ cnt, int* __restrict__ segs, int* __restrict__ cursor)
{
    __shared__ int part[1024];
    int t = threadIdx.x;
    int base = t * 16;
    int s = 0;
    #pragma unroll
    for (int i = 0; i < 16; ++i) s += cnt[base + i];
    part[t] = s;
    __syncthreads();
    for (int ofs = 1; ofs < 1024; ofs <<= 1) {
        int v = part[t];
        int add = (t >= ofs) ? part[t - ofs] : 0;
        __syncthreads();
        part[t] = v + add;
        __syncthreads();
    }
    int run = part[t] - s;
    #pragma unroll
    for (int i = 0; i < 16; ++i) {
        segs[base + i] = run;
        cursor[base + i] = run;
        run += cnt[base + i];
    }
    if (t == 1023) segs[NTOT] = run;
}

__global__ __launch_bounds__(256) void scatter_kernel(
    const int* __restrict__ ae, const float* __restrict__ aef, int* __restrict__ cursor,
    int* __restrict__ ssend, int* __restrict__ srecv, float* __restrict__ sdv)
{
    int g = blockIdx.x * 256 + threadIdx.x;
    int b = g >> 15;
    int sn = ae[2 * g] + b * NPER, rv = ae[2 * g + 1] + b * NPER;
    int pos = atomicAdd(&cursor[rv], 1);
    ssend[pos] = sn; srecv[pos] = rv;
    sdv[pos] = aef[g];
}

// ---------------- layer-0 node projections ----------------

__global__ __launch_bounds__(256, 3) void nodeproj_kernel(
    const unsigned short* __restrict__ nsb,
    const unsigned short* __restrict__ WT1, const float* __restrict__ bn1,
    unsigned* __restrict__ sprojP, unsigned* __restrict__ rprojP)
{
    __shared__ unsigned short Bs[2][64 * 128];
    const int tid = threadIdx.x;
    const int n0 = blockIdx.x * 64;
    const int wv = tid >> 6, l = tid & 63, l15 = l & 15, l4 = l >> 4;
    const int er = wv * 16 + l15, crow = wv * 16 + l4 * 4;

    short8 a[4];
    #pragma unroll
    for (int ks = 0; ks < 4; ++ks)
        a[ks] = *(const short8*)&nsb[(size_t)(n0 + er) * 128 + ks * 32 + l4 * 8];

    StageReg sr;
    stage_load(sr, WT1, 256, 0, tid);
    stage_write(sr, Bs[0], tid);
    __syncthreads();

    f32x4 cs[8] = {}, cr[8] = {};
    stage_load(sr, WT1, 256, 64, tid);
    #pragma unroll
    for (int ks = 0; ks < 2; ++ks)
        #pragma unroll
        for (int f = 0; f < 8; ++f)
            cs[f] = MFMA(a[ks], ldsB(Bs[0], f * 16 + l15, ks * 32 + l4 * 8), cs[f]);
    stage_write(sr, Bs[1], tid);
    __syncthreads();
    stage_load(sr, WT1, 256, 128, tid);
    #pragma unroll
    for (int ks = 0; ks < 2; ++ks)
        #pragma unroll
        for (int f = 0; f < 8; ++f)
            cs[f] = MFMA(a[2 + ks], ldsB(Bs[1], f * 16 + l15, ks * 32 + l4 * 8), cs[f]);
    stage_write(sr, Bs[0], tid);
    __syncthreads();
    stage_load(sr, WT1, 256, 192, tid);
    #pragma unroll
    for (int ks = 0; ks < 2; ++ks)
        #pragma unroll
        for (int f = 0; f < 8; ++f)
            cr[f] = MFMA(a[ks], ldsB(Bs[0], f * 16 + l15, ks * 32 + l4 * 8), cr[f]);
    stage_write(sr, Bs[1], tid);
    __syncthreads();
    #pragma unroll
    for (int ks = 0; ks < 2; ++ks)
        #pragma unroll
        for (int f = 0; f < 8; ++f)
            cr[f] = MFMA(a[2 + ks], ldsB(Bs[1], f * 16 + l15, ks * 32 + l4 * 8), cr[f]);

    #pragma unroll
    for (int fp = 0; fp < 4; ++fp) {
        float bl = bn1[fp * 32 + l15], bh = bn1[fp * 32 + 16 + l15];
        #pragma unroll
        for (int r = 0; r < 4; ++r) {
            size_t o = (size_t)(n0 + crow + r) * 64 + fp * 16 + l15;
            sprojP[o] = pk2(cs[2 * fp][r] + bl, cs[2 * fp + 1][r] + bh);
            rprojP[o] = pk2(cr[2 * fp][r], cr[2 * fp + 1][r]);
        }
    }
}

// ---------------- per-layer: edge messages + fused segment-sum (512 thr, all-loads-at-top) ----------------

__global__ __launch_bounds__(512, 6) void edge_mfma_kernel(
    const unsigned* __restrict__ sprojP, const unsigned* __restrict__ rprojP,
    const int* __restrict__ ssend, const int* __restrict__ srecv,
    const float* __restrict__ sdv,
    const unsigned short* __restrict__ WT2, const float* __restrict__ bn2,
    const unsigned* __restrict__ gtab,
    float* __restrict__ msum)
{
    __shared__ unsigned h1u[128 * 64];         // 32 KB: first 16 KB doubles as WT2 chunk1 panel, then messages
    __shared__ unsigned short Bs[64 * 128];    // 16 KB B panel (WT2 chunk0)
    __shared__ int rls[128];
    __shared__ short segstart[132];
    __shared__ int nseg_s;
    const int tid = threadIdx.x;
    const int e0 = blockIdx.x * 128;
    const int wv = tid >> 6, l = tid & 63, l15 = l & 15, l4 = l >> 4;
    const int er = wv * 16 + l15;
    const int crow = wv * 16 + l4 * 4;
    unsigned short* Bs1 = (unsigned short*)h1u;   // WT2 chunk1 lives here until combine

    // issue ALL global loads at the top: both WT2 halves + receivers
    StageRegH sr, sr2;
    stage_loadH(sr, WT2, 128, 0, tid);
    stage_loadH(sr2, WT2, 128, 64, tid);
    if (tid < 128) rls[tid] = srecv[e0 + tid];

    // gather + ssp directly into A-fragments (hides WT2 latency)
    const int sn = ssend[e0 + er], rn = srecv[e0 + er];
    short8 afr[4];
    #pragma unroll
    for (int ks = 0; ks < 4; ++ks) {
        uint4 sp = *(const uint4*)&sprojP[(size_t)sn * 64 + ks * 16 + l4 * 4];
        uint4 rp = *(const uint4*)&rprojP[(size_t)rn * 64 + ks * 16 + l4 * 4];
        unsigned su[4] = {sp.x, sp.y, sp.z, sp.w};
        unsigned ru[4] = {rp.x, rp.y, rp.z, rp.w};
        union { short8 s; unsigned u[4]; } A;
        #pragma unroll
        for (int j = 0; j < 4; ++j)
            A.u[j] = pk2(sspf(bflo(su[j]) + bflo(ru[j])),
                         sspf(bfhi(su[j]) + bfhi(ru[j])));
        afr[ks] = A.s;
    }
    stage_writeH(sr, Bs, tid);
    stage_writeH(sr2, Bs1, tid);
    __syncthreads();                           // barrier 1: both B panels ready

    if (wv == 7) {
        bool f0 = (l == 0) || (rls[l] != rls[l - 1]);
        bool f1 = (rls[64 + l] != rls[63 + l]);
        unsigned long long m0 = __ballot(f0);
        unsigned long long m1 = __ballot(f1);
        unsigned long long lm = (l == 63) ? 0xFFFFFFFFFFFFFFFFull >> 1
                                          : ((1ull << l) - 1);
        int n0c = __popcll(m0);
        if (f0) segstart[__popcll(m0 & lm)] = (short)l;
        if (f1) segstart[n0c + __popcll(m1 & lm)] = (short)(64 + l);
        if (l == 0) {
            int ns = n0c + __popcll(m1);
            nseg_s = ns;
            segstart[ns] = 128;
        }
    }

    int idxr[4];
    #pragma unroll
    for (int r = 0; r < 4; ++r) {
        float fia = sdv[e0 + crow + r] * ((float)GTN / 5.0f) + 0.5f;
        int ia = (int)fia; ia = (ia > GTN - 1) ? GTN - 1 : ia;
        idxr[r] = ia;
    }

    // GEMM: all 4 K-slices back-to-back, no internal barriers
    f32x4 m0f[8] = {};
    #pragma unroll
    for (int ks = 0; ks < 2; ++ks)
        #pragma unroll
        for (int f = 0; f < 8; ++f)
            m0f[f] = MFMA(afr[ks], ldsB(Bs, f * 16 + l15, ks * 32 + l4 * 8), m0f[f]);
    #pragma unroll
    for (int ks = 0; ks < 2; ++ks)
        #pragma unroll
        for (int f = 0; f < 8; ++f)
            m0f[f] = MFMA(afr[2 + ks], ldsB(Bs1, f * 16 + l15, ks * 32 + l4 * 8), m0f[f]);
    __syncthreads();                           // barrier 2: h1u B-panel reads done

    // combine: msg = (m + bn2) * gate_nn -> h1u (plain [128][64-dword] layout)
    #pragma unroll
    for (int r = 0; r < 4; ++r) {
        const unsigned* grow = gtab + (size_t)idxr[r] * 64;
        #pragma unroll
        for (int fp = 0; fp < 4; ++fp) {
            float bl = bn2[fp * 32 + l15], bh = bn2[fp * 32 + 16 + l15];
            unsigned g = grow[fp * 16 + l15];
            h1u[(crow + r) * 64 + fp * 16 + l15] =
                pk2((m0f[2 * fp][r] + bl) * bflo(g), (m0f[2 * fp + 1][r] + bh) * bfhi(g));
        }
    }
    __syncthreads();                           // barrier 3

    // fused segment-sum: per-wave segments, f32 accumulate from LDS, atomicAdd to msum
    {
        int ns = nseg_s;
        for (int s = wv; s < ns; s += 8) {
            int r0 = segstart[s], r1 = segstart[s + 1];
            int node = rls[r0];
            float lo = 0.0f, hi = 0.0f;
            for (int r = r0; r < r1; ++r) {
                unsigned v = h1u[r * 64 + l];
                lo += bflo(v); hi += bfhi(v);
            }
            float* dst = &msum[(size_t)node * 128 + l * 2];
            atomicAdd(dst, lo);
            atomicAdd(dst + 1, hi);
        }
    }
}

// ---------------- per-layer: state MLP + fused next-layer projection (512 thr, N-split) ----------------

__global__ __launch_bounds__(512, 2) void node_mfma_kernel(
    const float* __restrict__ msum,
    const unsigned short* __restrict__ WTs1, const float* __restrict__ bs1,
    const unsigned short* __restrict__ WTs2, const float* __restrict__ bs2,
    float* __restrict__ node_state, unsigned short* __restrict__ nsb,
    float* __restrict__ out_l,
    const unsigned short* __restrict__ WT1n, const float* __restrict__ bn1n,
    unsigned* __restrict__ sprojP, unsigned* __restrict__ rprojP, int doproj)
{
    __shared__ unsigned short ah[64 * 128];    // 16 KB act tile (swizzled)
    __shared__ unsigned short Bs[128 * 64];    // 16 KB B panel
    int tid = threadIdx.x;
    int n0 = blockIdx.x * 64;
    {
        const float2* ms2 = (const float2*)msum;
        #pragma unroll
        for (int it = 0; it < 8; ++it) {
            int idx = it * 512 + tid;
            int i = idx >> 6, u = idx & 63;
            float2 v = ms2[(size_t)(n0 + i) * 64 + u];
            *(unsigned*)((char*)ah + i * 256 + ((u * 4) ^ ((i & 7) << 4))) = pk2(v.x, v.y);
        }
    }
    __syncthreads();
    const int wv = tid >> 6, l = tid & 63, l15 = l & 15, l4 = l >> 4;
    const int rg = wv & 3, nh = wv >> 2;       // row-group, N-half
    const int er = rg * 16 + l15, crow = rg * 16 + l4 * 4;
    const int fb = nh * 4;                     // frag base (N-half)

    f32x4 c1[4] = {};
    #pragma unroll
    for (int c = 0; c < 2; ++c) {
        stage_b64_512(WTs1, 128, c * 64, Bs, tid);
        __syncthreads();
        #pragma unroll
        for (int ks = 0; ks < 2; ++ks) {
            short8 a = ldsA(ah, er, c * 64 + ks * 32 + l4 * 8);
            #pragma unroll
            for (int f = 0; f < 4; ++f)
                c1[f] = MFMA(a, ldsB(Bs, (fb + f) * 16 + l15, ks * 32 + l4 * 8), c1[f]);
        }
        __syncthreads();
    }
    #pragma unroll
    for (int fp = 0; fp < 2; ++fp) {
        int fpg = nh * 2 + fp;
        float bl = bs1[fpg * 32 + l15], bh = bs1[fpg * 32 + 16 + l15];
        #pragma unroll
        for (int r = 0; r < 4; ++r)
            actW(ah, crow + r, fpg * 16 + l15,
                 pk2(sspf(c1[2 * fp][r] + bl), sspf(c1[2 * fp + 1][r] + bh)));
    }
    __syncthreads();

    f32x4 c2[4] = {};
    #pragma unroll
    for (int c = 0; c < 2; ++c) {
        stage_b64_512(WTs2, 128, c * 64, Bs, tid);
        __syncthreads();
        #pragma unroll
        for (int ks = 0; ks < 2; ++ks) {
            short8 a = ldsA(ah, er, c * 64 + ks * 32 + l4 * 8);
            #pragma unroll
            for (int f = 0; f < 4; ++f)
                c2[f] = MFMA(a, ldsB(Bs, (fb + f) * 16 + l15, ks * 32 + l4 * 8), c2[f]);
        }
        __syncthreads();
    }

    // state update (this wave's 16 rows x its 64 features)
    unsigned nv[4][2];
    #pragma unroll
    for (int r = 0; r < 4; ++r) {
        int row = n0 + crow + r;
        float vv[4];
        #pragma unroll
        for (int f = 0; f < 4; ++f) {
            int n = (fb + f) * 16 + l15;
            float v = node_state[(size_t)row * 128 + n] + c2[f][r] + bs2[n];
            node_state[(size_t)row * 128 + n] = v;
            out_l[(size_t)row * 128 + n] = v;
            vv[f] = v;
        }
        #pragma unroll
        for (int fp = 0; fp < 2; ++fp) {
            unsigned p = pk2(vv[2 * fp], vv[2 * fp + 1]);
            nv[r][fp] = p;
            *(unsigned*)&nsb[(size_t)row * 128 + ((nh * 2 + fp) * 16 + l15) * 2] = p;
        }
    }

    if (!doproj) return;

    // re-stage new state into ah for next-layer projection GEMMs
    #pragma unroll
    for (int r = 0; r < 4; ++r)
        #pragma unroll
        for (int fp = 0; fp < 2; ++fp)
            actW(ah, crow + r, (nh * 2 + fp) * 16 + l15, nv[r][fp]);

    f32x4 cs[4] = {}, cr[4] = {};
    #pragma unroll
    for (int c = 0; c < 2; ++c) {
        stage_b64_512(WT1n, 256, c * 64, Bs, tid);
        __syncthreads();
        #pragma unroll
        for (int ks = 0; ks < 2; ++ks) {
            short8 a = ldsA(ah, er, c * 64 + ks * 32 + l4 * 8);
            #pragma unroll
            for (int f = 0; f < 4; ++f)
                cs[f] = MFMA(a, ldsB(Bs, (fb + f) * 16 + l15, ks * 32 + l4 * 8), cs[f]);
        }
        __syncthreads();
    }
    #pragma unroll
    for (int c = 0; c < 2; ++c) {
        stage_b64_512(WT1n, 256, 128 + c * 64, Bs, tid);
        __syncthreads();
        #pragma unroll
        for (int ks = 0; ks < 2; ++ks) {
            short8 a = ldsA(ah, er, c * 64 + ks * 32 + l4 * 8);
            #pragma unroll
            for (int f = 0; f < 4; ++f)
                cr[f] = MFMA(a, ldsB(Bs, (fb + f) * 16 + l15, ks * 32 + l4 * 8), cr[f]);
        }
        __syncthreads();
    }

    #pragma unroll
    for (int fp = 0; fp < 2; ++fp) {
        int fpg = nh * 2 + fp;
        float bl = bn1n[fpg * 32 + l15], bh = bn1n[fpg * 32 + 16 + l15];
        #pragma unroll
        for (int r = 0; r < 4; ++r) {
            size_t o = (size_t)(n0 + crow + r) * 64 + fpg * 16 + l15;
            sprojP[o] = pk2(cs[2 * fp][r] + bl, cs[2 * fp + 1][r] + bh);
            rprojP[o] = pk2(cr[2 * fp][r], cr[2 * fp + 1][r]);
        }
    }
}

// ---------------- host ----------------

extern "C" void kernel_launch(void* const* d_in, const int* in_sizes, int n_in,
                              void* d_out, int out_size, void* d_ws, size_t ws_size,
                              hipStream_t stream)
{
    const int*   nodes = (const int*)d_in[0];
    const int*   ae    = (const int*)d_in[1];
    const float* aef   = (const float*)d_in[2];
    const float* emb   = (const float*)d_in[5];
    const float* Wn1 = (const float*)d_in[6];  const float* bn1 = (const float*)d_in[7];
    const float* Wn2 = (const float*)d_in[8];  const float* bn2 = (const float*)d_in[9];
    const float* We1 = (const float*)d_in[10]; const float* be1 = (const float*)d_in[11];
    const float* We2 = (const float*)d_in[12]; const float* be2 = (const float*)d_in[13];
    const float* Ws1 = (const float*)d_in[14]; const float* bs1 = (const float*)d_in[15];
    const float* Ws2 = (const float*)d_in[16]; const float* bs2 = (const float*)d_in[17];
    float* out = (float*)d_out;

    char* ws = (char*)d_ws;
    const size_t MB = 1u << 20;
    float*          node_state = (float*)(ws);                    // 8 MB
    unsigned short* nsb        = (unsigned short*)(ws + 8 * MB);  // 4 MB
    float*          msum       = (float*)(ws + 12 * MB);          // 3 x 8 MB (f32) -- zeroed
    int*   cnt    = (int*)(ws + 36 * MB);                         // 64 KB          -- zeroed (contiguous with msum)
    int*   segs   = (int*)(ws + 36 * MB + 128 * 1024);
    int*   cursor = (int*)(ws + 36 * MB + 256 * 1024);
    int*   ssend  = (int*)(ws + 37 * MB);
    int*   srecv  = (int*)(ws + 38 * MB);
    float* sdv    = (float*)(ws + 39 * MB);
    unsigned short* WT1  = (unsigned short*)(ws + 40 * MB);       // 192 KB
    unsigned short* WT2  = (unsigned short*)(ws + 40 * MB + 256 * 1024);
    unsigned short* WTs1 = (unsigned short*)(ws + 41 * MB);
    unsigned short* WTs2 = (unsigned short*)(ws + 41 * MB + 256 * 1024);
    unsigned* sprojP = (unsigned*)(ws + 42 * MB);                 // 4 MB
    unsigned* rprojP = (unsigned*)(ws + 46 * MB);                 // 4 MB
    unsigned* gtab   = (unsigned*)(ws + 50 * MB);                 // 3 MB

    // zero msum (24 MB) + cnt (64 KB) in one fast grid-strided kernel
    {
        int n4 = (int)((24 * MB + 64 * 1024) / 16);
        zero_kernel<<<2048, 256, 0, stream>>>((float4*)msum, n4);
    }
    wprep_all_kernel<<<dim3((LNUM * 128 * 256 + 255) / 256, 4), 256, 0, stream>>>(
        Wn1, Wn2, Ws1, Ws2, WT1, WT2, WTs1, WTs2);
    gtab_kernel<<<dim3(GTN, LNUM), 128, 0, stream>>>(We1, be1, We2, be2, gtab);
    init_nodes_kernel<<<NTOT * 128 / 256, 256, 0, stream>>>(nodes, emb, node_state, nsb);
    count_kernel<<<ETOT / 256, 256, 0, stream>>>(ae, cnt);
    scan_kernel<<<1, 1024, 0, stream>>>(cnt, segs, cursor);
    scatter_kernel<<<ETOT / 256, 256, 0, stream>>>(ae, aef, cursor, ssend, srecv, sdv);

    nodeproj_kernel<<<NTOT / 64, 256, 0, stream>>>(nsb, WT1, bn1, sprojP, rprojP);

    for (int l = 0; l < LNUM; ++l) {
        float* msl = msum + (size_t)l * NTOT * 128;
        edge_mfma_kernel<<<ETOT / 128, 512, 0, stream>>>(
            sprojP, rprojP, ssend, srecv, sdv,
            WT2 + (size_t)l * 128 * 128, bn2 + (size_t)l * 128,
            gtab + (size_t)l * GTN * 64,
            msl);
        int nl = (l + 1 < LNUM) ? (l + 1) : 0;
        node_mfma_kernel<<<NTOT / 64, 512, 0, stream>>>(
            msl,
            WTs1 + (size_t)l * 128 * 128, bs1 + (size_t)l * 128,
            WTs2 + (size_t)l * 128 * 128, bs2 + (size_t)l * 128,
            node_state, nsb, out + (size_t)l * NTOT * 128,
            WT1 + (size_t)nl * 128 * 256, bn1 + (size_t)nl * 128,
            sprojP, rprojP, (l + 1 < LNUM) ? 1 : 0);
    }
}

// Round 19
// 225.507 us; speedup vs baseline: 1.3187x; 1.0562x over previous
//
#include <hip/hip_runtime.h>
#include <hip/hip_bf16.h>
#include <math.h>

#define BQ 8
#define NPER 2048
#define EPER 32768
#define NTOT (BQ * NPER)          // 16384
#define ETOT (BQ * EPER)          // 262144
#define HDIM 128
#define LNUM 3
#define GTN 4096                  // gate table entries over d in [0,5), nearest-neighbor

typedef __attribute__((ext_vector_type(8))) short short8;
typedef __attribute__((ext_vector_type(4))) float f32x4;

__device__ __forceinline__ short f2bf(float x) {
    union { float f; unsigned u; } v; v.f = x;
    unsigned r = v.u + 0x7fffu + ((v.u >> 16) & 1u);
    return (short)(r >> 16);
}
__device__ __forceinline__ unsigned pk2(float lo, float hi) {
    union { __hip_bfloat162 h; unsigned u; } v;
    float2 f; f.x = lo; f.y = hi;
    v.h = __float22bfloat162_rn(f);
    return v.u;
}
__device__ __forceinline__ float bflo(unsigned v) {
    union { unsigned u; float f; } x; x.u = v << 16; return x.f;
}
__device__ __forceinline__ float bfhi(unsigned v) {
    union { unsigned u; float f; } x; x.u = v & 0xffff0000u; return x.f;
}
// softplus(x)-ln2 via HW transcendentals
__device__ __forceinline__ float sspf(float x) {
    float e = __builtin_amdgcn_exp2f(x * 1.4426950408889634f);
    return 0.6931471805599453f * (__builtin_amdgcn_logf(1.0f + e) - 1.0f);
}
#define EXP2H(x) __builtin_amdgcn_exp2f(x)

// ---- LDS helpers (XOR-swizzled; act rows 256B, B rows 128B) ----
__device__ __forceinline__ short8 ldsA(const unsigned short* t, int row, int pos) {
    return *(const short8*)((const char*)t + row * 256 + ((pos * 2) ^ ((row & 7) << 4)));
}
__device__ __forceinline__ short8 ldsB(const unsigned short* t, int n, int pos) {
    return *(const short8*)((const char*)t + n * 128 + ((pos * 2) ^ ((n & 7) << 4)));
}
__device__ __forceinline__ void actW(unsigned short* t, int row, int dw, unsigned v) {
    *(unsigned*)((char*)t + row * 256 + ((dw * 4) ^ ((row & 7) << 4))) = v;
}

// ---- T14 async-STAGE split (256-thread, 16KB panel) ----
struct StageReg { uint4 v[4]; };
__device__ __forceinline__ void stage_load(StageReg& s, const unsigned short* __restrict__ src,
                                           int strideK, int kbase, int tid) {
    #pragma unroll
    for (int it = 0; it < 4; ++it) {
        int u = it * 256 + tid;
        int n = u >> 3, kd8 = u & 7;     // LINEAR source
        s.v[it] = *(const uint4*)&src[(size_t)n * strideK + kbase + kd8 * 8];
    }
}
__device__ __forceinline__ void stage_write(const StageReg& s, unsigned short* Bs, int tid) {
    #pragma unroll
    for (int it = 0; it < 4; ++it) {
        int u = it * 256 + tid;
        int n = u >> 3;
        *(uint4*)((char*)Bs + ((u * 16) ^ ((n & 7) << 4))) = s.v[it];
    }
}
// 512-thread 16KB-panel stager (8B units)
__device__ __forceinline__ void stage_b64_512(const unsigned short* __restrict__ src, int strideK, int kbase,
                                              unsigned short* __restrict__ Bs, int tid) {
    #pragma unroll
    for (int it = 0; it < 4; ++it) {
        int i = it * 512 + tid;
        int n = i >> 4, kd2 = i & 15;
        uint2 v = *(const uint2*)&src[(size_t)n * strideK + kbase + kd2 * 4];
        *(uint2*)((char*)Bs + n * 128 + ((kd2 * 8) ^ ((n & 7) << 4))) = v;
    }
}

// ---- 512-thread 16KB-panel stager (16B units, reg split) ----
struct StageRegH { uint4 v[2]; };
__device__ __forceinline__ void stage_loadH(StageRegH& s, const unsigned short* __restrict__ src,
                                            int strideK, int kbase, int tid) {
    #pragma unroll
    for (int it = 0; it < 2; ++it) {
        int u = it * 512 + tid;          // 1024 x 16B units
        int n = u >> 3, kd8 = u & 7;     // LINEAR source
        s.v[it] = *(const uint4*)&src[(size_t)n * strideK + kbase + kd8 * 8];
    }
}
__device__ __forceinline__ void stage_writeH(const StageRegH& s, unsigned short* Bs, int tid) {
    #pragma unroll
    for (int it = 0; it < 2; ++it) {
        int u = it * 512 + tid;
        int n = u >> 3;
        *(uint4*)((char*)Bs + ((u * 16) ^ ((n & 7) << 4))) = s.v[it];
    }
}

#define MFMA(A, B, C) __builtin_amdgcn_mfma_f32_16x16x32_bf16(A, B, C, 0, 0, 0)

// ---------------- once-per-launch prep (merged: zero | weights | init) ----------------

__global__ __launch_bounds__(256) void prep_kernel(
    float4* __restrict__ zdst, int n4,
    const float* __restrict__ Wn1, const float* __restrict__ Wn2,
    const float* __restrict__ Ws1, const float* __restrict__ Ws2,
    unsigned short* __restrict__ WT1, unsigned short* __restrict__ WT2,
    unsigned short* __restrict__ WTs1, unsigned short* __restrict__ WTs2,
    const int* __restrict__ nodes, const float* __restrict__ emb,
    float* __restrict__ node_state, unsigned short* __restrict__ nsb)
{
    const int idx = blockIdx.x * 256 + threadIdx.x;
    if (blockIdx.y == 0) {
        // zero msum (24 MB) + cnt (64 KB)
        float4 z = {0.0f, 0.0f, 0.0f, 0.0f};
        int stride = gridDim.x * 256;
        for (int i = idx; i < n4; i += stride) zdst[i] = z;
    } else if (blockIdx.y == 1) {
        // bf16 K-permuted transposes of Wn1(K=256), Wn2, Ws1, Ws2
        const float* W; unsigned short* WT; int K; int li;
        if (idx < LNUM * 128 * 256)           { W = Wn1; WT = WT1;  K = 256; li = idx; }
        else if (idx < LNUM * 128 * 384)      { W = Wn2; WT = WT2;  K = 128; li = idx - LNUM * 128 * 256; }
        else if (idx < LNUM * 128 * 512)      { W = Ws1; WT = WTs1; K = 128; li = idx - LNUM * 128 * 384; }
        else if (idx < LNUM * 128 * 640)      { W = Ws2; WT = WTs2; K = 128; li = idx - LNUM * 128 * 512; }
        else return;
        int l = li / (128 * K);
        int rem = li - l * (128 * K);
        int n = rem / K;
        int p = rem - n * K;
        int half = p >> 7, pp = p & 127;
        int k = (half << 7) | ((pp >> 5) << 5) | ((pp & 1) << 4) | ((pp & 31) >> 1);
        WT[li] = (unsigned short)f2bf(W[((size_t)l * K + k) * 128 + n]);
    } else {
        // init node state: 4 features per thread (2048 blocks x 256 x 4 = NTOT*128)
        int n = idx >> 5, q = idx & 31;
        int p0 = q * 4;
        const float* er = emb + (size_t)nodes[n] * 128;
        union { unsigned short s[4]; uint2 u; } b4;
        #pragma unroll
        for (int t = 0; t < 4; ++t) {
            int p = p0 + t;
            int j = ((p >> 5) << 5) | ((p & 1) << 4) | ((p & 31) >> 1);
            float v = er[j];
            b4.s[t] = (unsigned short)f2bf(v);
            node_state[((size_t)n << 7) + j] = v;
        }
        *(uint2*)&nsb[((size_t)n << 7) + p0] = b4.u;
    }
}

// gate table: gtab[l][idx][dword j] = bf16x2(gate*cut)
__global__ __launch_bounds__(128) void gtab_kernel(
    const float* __restrict__ We1, const float* __restrict__ be1,
    const float* __restrict__ We2, const float* __restrict__ be2,
    unsigned* __restrict__ gtab)
{
    const int idx = blockIdx.x, l = blockIdx.y, t = threadIdx.x;
    const float d = (float)idx * (5.0f / (float)GTN);
    __shared__ float rbf[64];
    __shared__ float hid[128];
    __shared__ float gv[128];
    if (t < 64) {
        float tt = d - 0.1f * (float)t;
        rbf[t] = (t < 50) ? EXP2H(-72.134752044448170f * tt * tt) : 0.0f;
    }
    __syncthreads();
    float acc = be1[l * 128 + t];
    for (int k = 0; k < 50; ++k)
        acc = fmaf(rbf[k], We1[((size_t)l * 50 + k) * 128 + t], acc);
    hid[t] = sspf(acc);
    __syncthreads();
    float g = be2[l * 128 + t];
    for (int k = 0; k < 128; ++k)
        g = fmaf(hid[k], We2[((size_t)l * 128 + k) * 128 + t], g);
    float cut = 1.0f / (1.0f + EXP2H(7.2134752044448170f * (d - 3.5f)));
    gv[t] = g * cut;
    __syncthreads();
    if (t < 64) {
        int fp = t >> 4, l15 = t & 15;
        gtab[((size_t)(l * GTN + idx)) * 64 + t] = pk2(gv[fp * 32 + l15], gv[fp * 32 + 16 + l15]);
    }
}

__global__ __launch_bounds__(256) void count_kernel(const int* __restrict__ ae, int* __restrict__ cnt)
{
    int g = blockIdx.x * 256 + threadIdx.x;
    int b = g >> 15;
    atomicAdd(&cnt[ae[2 * g + 1] + b * NPER], 1);
}

__global__ __launch_bounds__(1024) void scan_kernel(
    const int* __restrict__ cnt, int* __restrict__ segs, int* __restrict__ cursor)
{
    __shared__ int part[1024];
    int t = threadIdx.x;
    int base = t * 16;
    int s = 0;
    #pragma unroll
    for (int i = 0; i < 16; ++i) s += cnt[base + i];
    part[t] = s;
    __syncthreads();
    for (int ofs = 1; ofs < 1024; ofs <<= 1) {
        int v = part[t];
        int add = (t >= ofs) ? part[t - ofs] : 0;
        __syncthreads();
        part[t] = v + add;
        __syncthreads();
    }
    int run = part[t] - s;
    #pragma unroll
    for (int i = 0; i < 16; ++i) {
        segs[base + i] = run;
        cursor[base + i] = run;
        run += cnt[base + i];
    }
    if (t == 1023) segs[NTOT] = run;
}

__global__ __launch_bounds__(256) void scatter_kernel(
    const int* __restrict__ ae, const float* __restrict__ aef, int* __restrict__ cursor,
    int* __restrict__ ssend, int* __restrict__ srecv, float* __restrict__ sdv)
{
    int g = blockIdx.x * 256 + threadIdx.x;
    int b = g >> 15;
    int sn = ae[2 * g] + b * NPER, rv = ae[2 * g + 1] + b * NPER;
    int pos = atomicAdd(&cursor[rv], 1);
    ssend[pos] = sn; srecv[pos] = rv;
    sdv[pos] = aef[g];
}

// ---------------- layer-0 node projections ----------------

__global__ __launch_bounds__(256, 3) void nodeproj_kernel(
    const unsigned short* __restrict__ nsb,
    const unsigned short* __restrict__ WT1, const float* __restrict__ bn1,
    unsigned* __restrict__ sprojP, unsigned* __restrict__ rprojP)
{
    __shared__ unsigned short Bs[2][64 * 128];
    const int tid = threadIdx.x;
    const int n0 = blockIdx.x * 64;
    const int wv = tid >> 6, l = tid & 63, l15 = l & 15, l4 = l >> 4;
    const int er = wv * 16 + l15, crow = wv * 16 + l4 * 4;

    short8 a[4];
    #pragma unroll
    for (int ks = 0; ks < 4; ++ks)
        a[ks] = *(const short8*)&nsb[(size_t)(n0 + er) * 128 + ks * 32 + l4 * 8];

    StageReg sr;
    stage_load(sr, WT1, 256, 0, tid);
    stage_write(sr, Bs[0], tid);
    __syncthreads();

    f32x4 cs[8] = {}, cr[8] = {};
    stage_load(sr, WT1, 256, 64, tid);
    #pragma unroll
    for (int ks = 0; ks < 2; ++ks)
        #pragma unroll
        for (int f = 0; f < 8; ++f)
            cs[f] = MFMA(a[ks], ldsB(Bs[0], f * 16 + l15, ks * 32 + l4 * 8), cs[f]);
    stage_write(sr, Bs[1], tid);
    __syncthreads();
    stage_load(sr, WT1, 256, 128, tid);
    #pragma unroll
    for (int ks = 0; ks < 2; ++ks)
        #pragma unroll
        for (int f = 0; f < 8; ++f)
            cs[f] = MFMA(a[2 + ks], ldsB(Bs[1], f * 16 + l15, ks * 32 + l4 * 8), cs[f]);
    stage_write(sr, Bs[0], tid);
    __syncthreads();
    stage_load(sr, WT1, 256, 192, tid);
    #pragma unroll
    for (int ks = 0; ks < 2; ++ks)
        #pragma unroll
        for (int f = 0; f < 8; ++f)
            cr[f] = MFMA(a[ks], ldsB(Bs[0], f * 16 + l15, ks * 32 + l4 * 8), cr[f]);
    stage_write(sr, Bs[1], tid);
    __syncthreads();
    #pragma unroll
    for (int ks = 0; ks < 2; ++ks)
        #pragma unroll
        for (int f = 0; f < 8; ++f)
            cr[f] = MFMA(a[2 + ks], ldsB(Bs[1], f * 16 + l15, ks * 32 + l4 * 8), cr[f]);

    #pragma unroll
    for (int fp = 0; fp < 4; ++fp) {
        float bl = bn1[fp * 32 + l15], bh = bn1[fp * 32 + 16 + l15];
        #pragma unroll
        for (int r = 0; r < 4; ++r) {
            size_t o = (size_t)(n0 + crow + r) * 64 + fp * 16 + l15;
            sprojP[o] = pk2(cs[2 * fp][r] + bl, cs[2 * fp + 1][r] + bh);
            rprojP[o] = pk2(cr[2 * fp][r], cr[2 * fp + 1][r]);
        }
    }
}

// ---------------- per-layer: edge messages + fused segment-sum (512 thr, all-loads-at-top) ----------------

__global__ __launch_bounds__(512, 6) void edge_mfma_kernel(
    const unsigned* __restrict__ sprojP, const unsigned* __restrict__ rprojP,
    const int* __restrict__ ssend, const int* __restrict__ srecv,
    const float* __restrict__ sdv,
    const unsigned short* __restrict__ WT2, const float* __restrict__ bn2,
    const unsigned* __restrict__ gtab,
    float* __restrict__ msum)
{
    __shared__ unsigned h1u[128 * 64];         // 32 KB: first 16 KB doubles as WT2 chunk1 panel, then messages
    __shared__ unsigned short Bs[64 * 128];    // 16 KB B panel (WT2 chunk0)
    __shared__ int rls[128];
    __shared__ short segstart[132];
    __shared__ int nseg_s;
    const int tid = threadIdx.x;
    const int e0 = blockIdx.x * 128;
    const int wv = tid >> 6, l = tid & 63, l15 = l & 15, l4 = l >> 4;
    const int er = wv * 16 + l15;
    const int crow = wv * 16 + l4 * 4;
    unsigned short* Bs1 = (unsigned short*)h1u;   // WT2 chunk1 lives here until combine

    // issue ALL global loads at the top: both WT2 halves + receivers
    StageRegH sr, sr2;
    stage_loadH(sr, WT2, 128, 0, tid);
    stage_loadH(sr2, WT2, 128, 64, tid);
    if (tid < 128) rls[tid] = srecv[e0 + tid];

    // gather + ssp directly into A-fragments (hides WT2 latency)
    const int sn = ssend[e0 + er], rn = srecv[e0 + er];
    short8 afr[4];
    #pragma unroll
    for (int ks = 0; ks < 4; ++ks) {
        uint4 sp = *(const uint4*)&sprojP[(size_t)sn * 64 + ks * 16 + l4 * 4];
        uint4 rp = *(const uint4*)&rprojP[(size_t)rn * 64 + ks * 16 + l4 * 4];
        unsigned su[4] = {sp.x, sp.y, sp.z, sp.w};
        unsigned ru[4] = {rp.x, rp.y, rp.z, rp.w};
        union { short8 s; unsigned u[4]; } A;
        #pragma unroll
        for (int j = 0; j < 4; ++j)
            A.u[j] = pk2(sspf(bflo(su[j]) + bflo(ru[j])),
                         sspf(bfhi(su[j]) + bfhi(ru[j])));
        afr[ks] = A.s;
    }
    stage_writeH(sr, Bs, tid);
    stage_writeH(sr2, Bs1, tid);
    __syncthreads();                           // barrier 1: both B panels ready

    if (wv == 7) {
        bool f0 = (l == 0) || (rls[l] != rls[l - 1]);
        bool f1 = (rls[64 + l] != rls[63 + l]);
        unsigned long long m0 = __ballot(f0);
        unsigned long long m1 = __ballot(f1);
        unsigned long long lm = (l == 63) ? 0xFFFFFFFFFFFFFFFFull >> 1
                                          : ((1ull << l) - 1);
        int n0c = __popcll(m0);
        if (f0) segstart[__popcll(m0 & lm)] = (short)l;
        if (f1) segstart[n0c + __popcll(m1 & lm)] = (short)(64 + l);
        if (l == 0) {
            int ns = n0c + __popcll(m1);
            nseg_s = ns;
            segstart[ns] = 128;
        }
    }

    int idxr[4];
    #pragma unroll
    for (int r = 0; r < 4; ++r) {
        float fia = sdv[e0 + crow + r] * ((float)GTN / 5.0f) + 0.5f;
        int ia = (int)fia; ia = (ia > GTN - 1) ? GTN - 1 : ia;
        idxr[r] = ia;
    }

    // GEMM: all 4 K-slices back-to-back, no internal barriers (T5 setprio around cluster)
    f32x4 m0f[8] = {};
    __builtin_amdgcn_s_setprio(1);
    #pragma unroll
    for (int ks = 0; ks < 2; ++ks)
        #pragma unroll
        for (int f = 0; f < 8; ++f)
            m0f[f] = MFMA(afr[ks], ldsB(Bs, f * 16 + l15, ks * 32 + l4 * 8), m0f[f]);
    #pragma unroll
    for (int ks = 0; ks < 2; ++ks)
        #pragma unroll
        for (int f = 0; f < 8; ++f)
            m0f[f] = MFMA(afr[2 + ks], ldsB(Bs1, f * 16 + l15, ks * 32 + l4 * 8), m0f[f]);
    __builtin_amdgcn_s_setprio(0);
    __syncthreads();                           // barrier 2: h1u B-panel reads done

    // combine: msg = (m + bn2) * gate_nn -> h1u (plain [128][64-dword] layout)
    #pragma unroll
    for (int r = 0; r < 4; ++r) {
        const unsigned* grow = gtab + (size_t)idxr[r] * 64;
        #pragma unroll
        for (int fp = 0; fp < 4; ++fp) {
            float bl = bn2[fp * 32 + l15], bh = bn2[fp * 32 + 16 + l15];
            unsigned g = grow[fp * 16 + l15];
            h1u[(crow + r) * 64 + fp * 16 + l15] =
                pk2((m0f[2 * fp][r] + bl) * bflo(g), (m0f[2 * fp + 1][r] + bh) * bfhi(g));
        }
    }
    __syncthreads();                           // barrier 3

    // fused segment-sum: per-wave segments, f32 accumulate from LDS, atomicAdd to msum
    {
        int ns = nseg_s;
        for (int s = wv; s < ns; s += 8) {
            int r0 = segstart[s], r1 = segstart[s + 1];
            int node = rls[r0];
            float lo = 0.0f, hi = 0.0f;
            for (int r = r0; r < r1; ++r) {
                unsigned v = h1u[r * 64 + l];
                lo += bflo(v); hi += bfhi(v);
            }
            float* dst = &msum[(size_t)node * 128 + l * 2];
            atomicAdd(dst, lo);
            atomicAdd(dst + 1, hi);
        }
    }
}

// ---------------- per-layer: state MLP + fused next-layer projection (512 thr, N-split) ----------------

__global__ __launch_bounds__(512, 2) void node_mfma_kernel(
    const float* __restrict__ msum,
    const unsigned short* __restrict__ WTs1, const float* __restrict__ bs1,
    const unsigned short* __restrict__ WTs2, const float* __restrict__ bs2,
    float* __restrict__ node_state, unsigned short* __restrict__ nsb,
    float* __restrict__ out_l,
    const unsigned short* __restrict__ WT1n, const float* __restrict__ bn1n,
    unsigned* __restrict__ sprojP, unsigned* __restrict__ rprojP, int doproj)
{
    __shared__ unsigned short ah[64 * 128];    // 16 KB act tile (swizzled)
    __shared__ unsigned short Bs[128 * 64];    // 16 KB B panel
    int tid = threadIdx.x;
    int n0 = blockIdx.x * 64;
    {
        const float2* ms2 = (const float2*)msum;
        #pragma unroll
        for (int it = 0; it < 8; ++it) {
            int idx = it * 512 + tid;
            int i = idx >> 6, u = idx & 63;
            float2 v = ms2[(size_t)(n0 + i) * 64 + u];
            *(unsigned*)((char*)ah + i * 256 + ((u * 4) ^ ((i & 7) << 4))) = pk2(v.x, v.y);
        }
    }
    __syncthreads();
    const int wv = tid >> 6, l = tid & 63, l15 = l & 15, l4 = l >> 4;
    const int rg = wv & 3, nh = wv >> 2;       // row-group, N-half
    const int er = rg * 16 + l15, crow = rg * 16 + l4 * 4;
    const int fb = nh * 4;                     // frag base (N-half)

    f32x4 c1[4] = {};
    #pragma unroll
    for (int c = 0; c < 2; ++c) {
        stage_b64_512(WTs1, 128, c * 64, Bs, tid);
        __syncthreads();
        #pragma unroll
        for (int ks = 0; ks < 2; ++ks) {
            short8 a = ldsA(ah, er, c * 64 + ks * 32 + l4 * 8);
            #pragma unroll
            for (int f = 0; f < 4; ++f)
                c1[f] = MFMA(a, ldsB(Bs, (fb + f) * 16 + l15, ks * 32 + l4 * 8), c1[f]);
        }
        __syncthreads();
    }
    #pragma unroll
    for (int fp = 0; fp < 2; ++fp) {
        int fpg = nh * 2 + fp;
        float bl = bs1[fpg * 32 + l15], bh = bs1[fpg * 32 + 16 + l15];
        #pragma unroll
        for (int r = 0; r < 4; ++r)
            actW(ah, crow + r, fpg * 16 + l15,
                 pk2(sspf(c1[2 * fp][r] + bl), sspf(c1[2 * fp + 1][r] + bh)));
    }
    __syncthreads();

    f32x4 c2[4] = {};
    #pragma unroll
    for (int c = 0; c < 2; ++c) {
        stage_b64_512(WTs2, 128, c * 64, Bs, tid);
        __syncthreads();
        #pragma unroll
        for (int ks = 0; ks < 2; ++ks) {
            short8 a = ldsA(ah, er, c * 64 + ks * 32 + l4 * 8);
            #pragma unroll
            for (int f = 0; f < 4; ++f)
                c2[f] = MFMA(a, ldsB(Bs, (fb + f) * 16 + l15, ks * 32 + l4 * 8), c2[f]);
        }
        __syncthreads();
    }

    // state update (this wave's 16 rows x its 64 features)
    unsigned nv[4][2];
    #pragma unroll
    for (int r = 0; r < 4; ++r) {
        int row = n0 + crow + r;
        float vv[4];
        #pragma unroll
        for (int f = 0; f < 4; ++f) {
            int n = (fb + f) * 16 + l15;
            float v = node_state[(size_t)row * 128 + n] + c2[f][r] + bs2[n];
            node_state[(size_t)row * 128 + n] = v;
            out_l[(size_t)row * 128 + n] = v;
            vv[f] = v;
        }
        #pragma unroll
        for (int fp = 0; fp < 2; ++fp) {
            unsigned p = pk2(vv[2 * fp], vv[2 * fp + 1]);
            nv[r][fp] = p;
            *(unsigned*)&nsb[(size_t)row * 128 + ((nh * 2 + fp) * 16 + l15) * 2] = p;
        }
    }

    if (!doproj) return;

    // re-stage new state into ah for next-layer projection GEMMs
    #pragma unroll
    for (int r = 0; r < 4; ++r)
        #pragma unroll
        for (int fp = 0; fp < 2; ++fp)
            actW(ah, crow + r, (nh * 2 + fp) * 16 + l15, nv[r][fp]);

    f32x4 cs[4] = {}, cr[4] = {};
    #pragma unroll
    for (int c = 0; c < 2; ++c) {
        stage_b64_512(WT1n, 256, c * 64, Bs, tid);
        __syncthreads();
        #pragma unroll
        for (int ks = 0; ks < 2; ++ks) {
            short8 a = ldsA(ah, er, c * 64 + ks * 32 + l4 * 8);
            #pragma unroll
            for (int f = 0; f < 4; ++f)
                cs[f] = MFMA(a, ldsB(Bs, (fb + f) * 16 + l15, ks * 32 + l4 * 8), cs[f]);
        }
        __syncthreads();
    }
    #pragma unroll
    for (int c = 0; c < 2; ++c) {
        stage_b64_512(WT1n, 256, 128 + c * 64, Bs, tid);
        __syncthreads();
        #pragma unroll
        for (int ks = 0; ks < 2; ++ks) {
            short8 a = ldsA(ah, er, c * 64 + ks * 32 + l4 * 8);
            #pragma unroll
            for (int f = 0; f < 4; ++f)
                cr[f] = MFMA(a, ldsB(Bs, (fb + f) * 16 + l15, ks * 32 + l4 * 8), cr[f]);
        }
        __syncthreads();
    }

    #pragma unroll
    for (int fp = 0; fp < 2; ++fp) {
        int fpg = nh * 2 + fp;
        float bl = bn1n[fpg * 32 + l15], bh = bn1n[fpg * 32 + 16 + l15];
        #pragma unroll
        for (int r = 0; r < 4; ++r) {
            size_t o = (size_t)(n0 + crow + r) * 64 + fpg * 16 + l15;
            sprojP[o] = pk2(cs[2 * fp][r] + bl, cs[2 * fp + 1][r] + bh);
            rprojP[o] = pk2(cr[2 * fp][r], cr[2 * fp + 1][r]);
        }
    }
}

// ---------------- host ----------------

extern "C" void kernel_launch(void* const* d_in, const int* in_sizes, int n_in,
                              void* d_out, int out_size, void* d_ws, size_t ws_size,
                              hipStream_t stream)
{
    const int*   nodes = (const int*)d_in[0];
    const int*   ae    = (const int*)d_in[1];
    const float* aef   = (const float*)d_in[2];
    const float* emb   = (const float*)d_in[5];
    const float* Wn1 = (const float*)d_in[6];  const float* bn1 = (const float*)d_in[7];
    const float* Wn2 = (const float*)d_in[8];  const float* bn2 = (const float*)d_in[9];
    const float* We1 = (const float*)d_in[10]; const float* be1 = (const float*)d_in[11];
    const float* We2 = (const float*)d_in[12]; const float* be2 = (const float*)d_in[13];
    const float* Ws1 = (const float*)d_in[14]; const float* bs1 = (const float*)d_in[15];
    const float* Ws2 = (const float*)d_in[16]; const float* bs2 = (const float*)d_in[17];
    float* out = (float*)d_out;

    char* ws = (char*)d_ws;
    const size_t MB = 1u << 20;
    float*          node_state = (float*)(ws);                    // 8 MB
    unsigned short* nsb        = (unsigned short*)(ws + 8 * MB);  // 4 MB
    float*          msum       = (float*)(ws + 12 * MB);          // 3 x 8 MB (f32) -- zeroed
    int*   cnt    = (int*)(ws + 36 * MB);                         // 64 KB          -- zeroed (contiguous with msum)
    int*   segs   = (int*)(ws + 36 * MB + 128 * 1024);
    int*   cursor = (int*)(ws + 36 * MB + 256 * 1024);
    int*   ssend  = (int*)(ws + 37 * MB);
    int*   srecv  = (int*)(ws + 38 * MB);
    float* sdv    = (float*)(ws + 39 * MB);
    unsigned short* WT1  = (unsigned short*)(ws + 40 * MB);       // 192 KB
    unsigned short* WT2  = (unsigned short*)(ws + 40 * MB + 256 * 1024);
    unsigned short* WTs1 = (unsigned short*)(ws + 41 * MB);
    unsigned short* WTs2 = (unsigned short*)(ws + 41 * MB + 256 * 1024);
    unsigned* sprojP = (unsigned*)(ws + 42 * MB);                 // 4 MB
    unsigned* rprojP = (unsigned*)(ws + 46 * MB);                 // 4 MB
    unsigned* gtab   = (unsigned*)(ws + 50 * MB);                 // 3 MB

    // merged prep: zero(msum+cnt) | weight transposes | node init  (one launch)
    {
        int n4 = (int)((24 * MB + 64 * 1024) / 16);
        prep_kernel<<<dim3(2048, 3), 256, 0, stream>>>(
            (float4*)msum, n4,
            Wn1, Wn2, Ws1, Ws2, WT1, WT2, WTs1, WTs2,
            nodes, emb, node_state, nsb);
    }
    gtab_kernel<<<dim3(GTN, LNUM), 128, 0, stream>>>(We1, be1, We2, be2, gtab);
    count_kernel<<<ETOT / 256, 256, 0, stream>>>(ae, cnt);
    scan_kernel<<<1, 1024, 0, stream>>>(cnt, segs, cursor);
    scatter_kernel<<<ETOT / 256, 256, 0, stream>>>(ae, aef, cursor, ssend, srecv, sdv);

    nodeproj_kernel<<<NTOT / 64, 256, 0, stream>>>(nsb, WT1, bn1, sprojP, rprojP);

    for (int l = 0; l < LNUM; ++l) {
        float* msl = msum + (size_t)l * NTOT * 128;
        edge_mfma_kernel<<<ETOT / 128, 512, 0, stream>>>(
            sprojP, rprojP, ssend, srecv, sdv,
            WT2 + (size_t)l * 128 * 128, bn2 + (size_t)l * 128,
            gtab + (size_t)l * GTN * 64,
            msl);
        int nl = (l + 1 < LNUM) ? (l + 1) : 0;
        node_mfma_kernel<<<NTOT / 64, 512, 0, stream>>>(
            msl,
            WTs1 + (size_t)l * 128 * 128, bs1 + (size_t)l * 128,
            WTs2 + (size_t)l * 128 * 128, bs2 + (size_t)l * 128,
            node_state, nsb, out + (size_t)l * NTOT * 128,
            WT1 + (size_t)nl * 128 * 256, bn1 + (size_t)nl * 128,
            sprojP, rprojP, (l + 1 < LNUM) ? 1 : 0);
    }
}